// Round 7
// baseline (14916.864 us; speedup 1.0000x reference)
//
#include <hip/hip_runtime.h>
#include <hip/hip_cooperative_groups.h>
#include <stdint.h>

namespace cg = cooperative_groups;

#define BB 64
#define DD 512
#define HH 1024
#define VV 32000
#define T_STEPS 50
#define G3 3072
#define NT 500      // logits col-tiles (64 cols each)
#define NGH 48      // gate col-tiles (64 cols each, 3072/64)
#define LP 42       // LDS row stride (ushorts): 21 dwords, gcd(21,32)=1 -> ~conflict-free

typedef __attribute__((ext_vector_type(8))) short bf16x8;
typedef __attribute__((ext_vector_type(4))) float f32x4;
typedef unsigned long long u64;
typedef unsigned short ushort_t;

__device__ __forceinline__ uint32_t rotl32(uint32_t x, int d) {
  return (x << d) | (x >> (32 - d));
}

// JAX threefry2x32 (20 rounds) — verified exact in rounds 1-6.
__device__ __forceinline__ void threefry2x32(uint32_t k0, uint32_t k1,
                                             uint32_t& x0, uint32_t& x1) {
  uint32_t ks0 = k0, ks1 = k1, ks2 = k0 ^ k1 ^ 0x1BD11BDAu;
  x0 += ks0; x1 += ks1;
#define TF_R(r) { x0 += x1; x1 = rotl32(x1, (r)); x1 ^= x0; }
  TF_R(13) TF_R(15) TF_R(26) TF_R(6)
  x0 += ks1; x1 += ks2 + 1u;
  TF_R(17) TF_R(29) TF_R(16) TF_R(24)
  x0 += ks2; x1 += ks0 + 2u;
  TF_R(13) TF_R(15) TF_R(26) TF_R(6)
  x0 += ks0; x1 += ks1 + 3u;
  TF_R(17) TF_R(29) TF_R(16) TF_R(24)
  x0 += ks1; x1 += ks2 + 4u;
  TF_R(13) TF_R(15) TF_R(26) TF_R(6)
  x0 += ks2; x1 += ks0 + 5u;
#undef TF_R
}

__device__ __forceinline__ uint32_t f2bf(float f) {
  uint32_t u = __float_as_uint(f);
  return (u + 0x7fffu + ((u >> 16) & 1u)) >> 16;
}
__device__ __forceinline__ float bf2f(uint32_t b) { return __uint_as_float(b << 16); }

__device__ __forceinline__ u64 packkey(float v, int c) {
  uint32_t s = __float_as_uint(v);
  uint32_t mo = (s & 0x80000000u) ? ~s : (s | 0x80000000u);
  return ((u64)mo << 32) | (uint32_t)(~(uint32_t)c);
}
__device__ __forceinline__ u64 umax64(u64 a, u64 b) { return a > b ? a : b; }

union BF8 { uint32_t u[4]; bf16x8 v; };

__device__ __forceinline__ void split8(const float* f, bf16x8& hi, bf16x8& lo) {
  BF8 H, L;
#pragma unroll
  for (int i = 0; i < 4; ++i) {
    float a = f[2 * i], b = f[2 * i + 1];
    uint32_t ha = f2bf(a), hb = f2bf(b);
    float ra = a - bf2f(ha), rb = b - bf2f(hb);
    H.u[i] = ha | (hb << 16);
    L.u[i] = f2bf(ra) | (f2bf(rb) << 16);
  }
  hi = H.v; lo = L.v;
}

__device__ __forceinline__ void split_store4(const float4 v, ushort_t* hi,
                                             ushort_t* lo, long i) {
  uint32_t h0 = f2bf(v.x), h1 = f2bf(v.y), h2 = f2bf(v.z), h3 = f2bf(v.w);
  uint32_t l0 = f2bf(v.x - bf2f(h0)), l1 = f2bf(v.y - bf2f(h1));
  uint32_t l2 = f2bf(v.z - bf2f(h2)), l3 = f2bf(v.w - bf2f(h3));
  *(uint2*)(hi + i) = make_uint2(h0 | (h1 << 16), h2 | (h3 << 16));
  *(uint2*)(lo + i) = make_uint2(l0 | (l1 << 16), l2 | (l3 << 16));
}

__device__ void split_arr(const float* __restrict__ s, ushort_t* __restrict__ hi,
                          ushort_t* __restrict__ lo, long n, long st, long stride) {
  for (long i = st; i < n; i += stride) {
    float4 v = *(const float4*)(s + i);
    split_store4(v, hi, lo, i);
  }
}

// Proven 256-thread 64x64 tile: LDS-staged B (pre-split bf16 hi/lo),
// padded [64][LP] layout, 2x2 wave quadrants, 3-term split-precision MFMA.
template<bool AGATHER>
__device__ __forceinline__ void tile256(
    ushort_t (*__restrict__ bhS)[LP], ushort_t (*__restrict__ blS)[LP],
    const ushort_t* __restrict__ Ahi, const ushort_t* __restrict__ Alo,
    const float* __restrict__ Ag, const int* __restrict__ rowidx, int lda,
    const ushort_t* __restrict__ Bhi, const ushort_t* __restrict__ Blo,
    int K, int n0, f32x4 acc[2][2])
{
  const int tid = threadIdx.x, lane = tid & 63, w = tid >> 6;
  const int l15 = lane & 15, q = lane >> 4;
  const int rw = (w >> 1) * 32, cw = (w & 1) * 32;
  const int srow = tid >> 2, schunk = (tid & 3) * 8;

  size_t abase[2];
#pragma unroll
  for (int m = 0; m < 2; ++m) {
    int r = rw + 16 * m + l15;
    abase[m] = (size_t)(AGATHER ? rowidx[r] : r) * lda + 8 * q;
  }
  const size_t bstage = (size_t)(n0 + srow) * K + schunk;

  for (int k0 = 0; k0 < K; k0 += 32) {
    bf16x8 bh8 = *(const bf16x8*)(Bhi + bstage + k0);
    bf16x8 bl8 = *(const bf16x8*)(Blo + bstage + k0);

    bf16x8 ah[2], al[2];
#pragma unroll
    for (int m = 0; m < 2; ++m) {
      if constexpr (AGATHER) {
        const float* ap = Ag + abase[m] + k0;
        float4 a0 = *(const float4*)ap;
        float4 a1 = *(const float4*)(ap + 4);
        float f[8] = {a0.x, a0.y, a0.z, a0.w, a1.x, a1.y, a1.z, a1.w};
        split8(f, ah[m], al[m]);
      } else {
        ah[m] = *(const bf16x8*)(Ahi + abase[m] + k0);
        al[m] = *(const bf16x8*)(Alo + abase[m] + k0);
      }
    }

    __syncthreads();
    *(bf16x8*)&bhS[srow][schunk] = bh8;
    *(bf16x8*)&blS[srow][schunk] = bl8;
    __syncthreads();

    bf16x8 bhf[2], blf[2];
#pragma unroll
    for (int n = 0; n < 2; ++n) {
      bhf[n] = *(const bf16x8*)&bhS[cw + 16 * n + l15][8 * q];
      blf[n] = *(const bf16x8*)&blS[cw + 16 * n + l15][8 * q];
    }
#pragma unroll
    for (int m = 0; m < 2; ++m)
#pragma unroll
      for (int n = 0; n < 2; ++n) {
        acc[m][n] = __builtin_amdgcn_mfma_f32_16x16x32_bf16(ah[m], bhf[n], acc[m][n], 0, 0, 0);
        acc[m][n] = __builtin_amdgcn_mfma_f32_16x16x32_bf16(ah[m], blf[n], acc[m][n], 0, 0, 0);
        acc[m][n] = __builtin_amdgcn_mfma_f32_16x16x32_bf16(al[m], bhf[n], acc[m][n], 0, 0, 0);
      }
  }
}

__device__ __forceinline__ void store_tile256(f32x4 acc[2][2], float* __restrict__ C,
                                              int ldc, int n0)
{
  const int tid = threadIdx.x, lane = tid & 63, w = tid >> 6;
  const int l15 = lane & 15, q = lane >> 4;
  const int rw = (w >> 1) * 32, cw = (w & 1) * 32;
#pragma unroll
  for (int m = 0; m < 2; ++m)
#pragma unroll
    for (int n = 0; n < 2; ++n)
#pragma unroll
      for (int r = 0; r < 4; ++r)
        C[(size_t)(rw + 16 * m + 4 * q + r) * ldc + n0 + cw + 16 * n + l15] = acc[m][n][r];
}

// logits store(+bias, nontemporal) + fused gumbel-argmax partial -> partial[job][row]
__device__ __forceinline__ void sample_epi256(
    f32x4 acc[2][2], u64 (*__restrict__ scr)[2],
    const float* __restrict__ bias, float* __restrict__ C, int n0,
    u64* __restrict__ partial, int job, int t)
{
  const int tid = threadIdx.x, lane = tid & 63, w = tid >> 6;
  const int l15 = lane & 15, q = lane >> 4;
  const int rw = (w >> 1) * 32, cw = (w & 1) * 32;

  uint32_t kt0 = 0u, kt1 = (uint32_t)t;
  threefry2x32(0u, 42u, kt0, kt1);

  u64 bk[2][4];
#pragma unroll
  for (int m = 0; m < 2; ++m)
#pragma unroll
    for (int r = 0; r < 4; ++r) bk[m][r] = 0ull;

#pragma unroll
  for (int m = 0; m < 2; ++m)
#pragma unroll
    for (int n = 0; n < 2; ++n)
#pragma unroll
      for (int r = 0; r < 4; ++r) {
        int row = rw + 16 * m + 4 * q + r;          // batch index
        int col = n0 + cw + 16 * n + l15;           // vocab index
        float val = acc[m][n][r] + bias[col];
        __builtin_nontemporal_store(val, &C[(size_t)row * VV + col]);
        uint32_t c0 = 0u, c1 = (uint32_t)(row * VV + col);
        threefry2x32(kt0, kt1, c0, c1);
        uint32_t bits = c0 ^ c1;
        float u = __uint_as_float((bits >> 9) | 0x3f800000u) - 1.0f;
        if (u == 0.0f) u = 1.17549435e-38f;
        float g = -__logf(-__logf(u));
        bk[m][r] = umax64(bk[m][r], packkey(val + g, col));
      }
#pragma unroll
  for (int off = 1; off < 16; off <<= 1)
#pragma unroll
    for (int m = 0; m < 2; ++m)
#pragma unroll
      for (int r = 0; r < 4; ++r)
        bk[m][r] = umax64(bk[m][r], (u64)__shfl_xor((long long)bk[m][r], off, 64));

  if (l15 == 0) {
#pragma unroll
    for (int m = 0; m < 2; ++m)
#pragma unroll
      for (int r = 0; r < 4; ++r)
        scr[rw + 16 * m + 4 * q + r][w & 1] = bk[m][r];
  }
  __syncthreads();
  if (tid < 64)
    partial[(size_t)job * 64 + tid] = umax64(scr[tid][0], scr[tid][1]);
  __syncthreads();
}

// block-local: reduce partial[500][64] -> idxS[64]; k<0 => eos
__device__ __forceinline__ void reduce_idx(
    int k, int eosv, const u64* __restrict__ partial,
    u64 (*__restrict__ fin)[4], int* __restrict__ idxS,
    float* __restrict__ idx_out, bool writeOut)
{
  const int tid = threadIdx.x;
  if (k < 0) {
    if (tid < 64) idxS[tid] = eosv;
    __syncthreads();
    return;
  }
  const int row = tid & 63, sub = tid >> 6;
  u64 best = 0;
  for (int i = sub; i < NT; i += 4)
    best = umax64(best, partial[(size_t)i * 64 + row]);
  fin[row][sub] = best;
  __syncthreads();
  if (tid < 64) {
    u64 b = umax64(umax64(fin[tid][0], fin[tid][1]),
                   umax64(fin[tid][2], fin[tid][3]));
    int idx = (int)(~(uint32_t)b);
    idxS[tid] = idx;
    if (writeOut) idx_out[(size_t)k * BB + tid] = (float)idx;
  }
  __syncthreads();
}

__device__ __forceinline__ void gh_job(
    int g, const ushort_t* __restrict__ hhi, const ushort_t* __restrict__ hlo,
    const ushort_t* __restrict__ whhH, const ushort_t* __restrict__ whhL,
    float* __restrict__ gh,
    ushort_t (*__restrict__ bhS)[LP], ushort_t (*__restrict__ blS)[LP])
{
  f32x4 acc[2][2] = {};
  tile256<false>(bhS, blS, hhi, hlo, nullptr, nullptr, HH, whhH, whhL, HH, g * 64, acc);
  store_tile256(acc, gh, G3, g * 64);
}

__device__ __forceinline__ void gi_job(
    int g, const float* __restrict__ emb, const int* __restrict__ idxS,
    const ushort_t* __restrict__ wihH, const ushort_t* __restrict__ wihL,
    float* __restrict__ gi,
    ushort_t (*__restrict__ bhS)[LP], ushort_t (*__restrict__ blS)[LP])
{
  f32x4 acc[2][2] = {};
  tile256<true>(bhS, blS, nullptr, nullptr, emb, idxS, DD, wihH, wihL, DD, g * 64, acc);
  store_tile256(acc, gi, G3, g * 64);
}

__device__ __forceinline__ void fuse_all(
    int bid, int GRD,
    const float* __restrict__ gi, const float* __restrict__ gh,
    const float* __restrict__ bih, const float* __restrict__ bhh,
    float* __restrict__ h, ushort_t* __restrict__ hhi, ushort_t* __restrict__ hlo)
{
  for (int i = bid * 256 + threadIdx.x; i < BB * HH; i += GRD * 256) {
    int b = i >> 10, j = i & 1023;
    const float* gir = gi + (size_t)b * G3;
    const float* ghr = gh + (size_t)b * G3;
    float ir  = gir[j]        + bih[j],        hr = ghr[j]        + bhh[j];
    float iz  = gir[j + 1024] + bih[j + 1024], hz = ghr[j + 1024] + bhh[j + 1024];
    float in_ = gir[j + 2048] + bih[j + 2048], hn = ghr[j + 2048] + bhh[j + 2048];
    float r = 1.f / (1.f + expf(-(ir + hr)));
    float z = 1.f / (1.f + expf(-(iz + hz)));
    float n = tanhf(in_ + r * hn);
    float hv = (1.f - z) * n + z * h[i];
    h[i] = hv;
    uint32_t hb = f2bf(hv);
    hhi[i] = (ushort_t)hb;
    hlo[i] = (ushort_t)f2bf(hv - bf2f(hb));
  }
}

__device__ __forceinline__ void prologue_body(
    const float* __restrict__ seq, const float* __restrict__ Wih,
    const float* __restrict__ Whh, const float* __restrict__ fcw,
    float* __restrict__ h0, ushort_t* __restrict__ h0hi, ushort_t* __restrict__ h0lo,
    ushort_t* __restrict__ wihH, ushort_t* __restrict__ wihL,
    ushort_t* __restrict__ whhH, ushort_t* __restrict__ whhL,
    ushort_t* __restrict__ fcwH, ushort_t* __restrict__ fcwL)
{
  long st = 4L * ((long)blockIdx.x * blockDim.x + threadIdx.x);
  long stride = 4L * (long)gridDim.x * blockDim.x;
  split_arr(Wih, wihH, wihL, (long)G3 * DD, st, stride);
  split_arr(Whh, whhH, whhL, (long)G3 * HH, st, stride);
  split_arr(fcw, fcwH, fcwL, (long)VV * HH, st, stride);
  for (long i = st; i < BB * HH; i += stride) {
    float4 v = *(const float4*)(seq + i);
    *(float4*)(h0 + i) = v;
    split_store4(v, h0hi, h0lo, i);
  }
}

// ---------------- cooperative mega-kernel (3 syncs/step pipeline) ----------------
__global__ __launch_bounds__(256, 4) void decoder_all(
    const float* __restrict__ seq, const float* __restrict__ emb,
    const float* __restrict__ Wih, const float* __restrict__ Whh,
    const float* __restrict__ bih, const float* __restrict__ bhh,
    const float* __restrict__ fcw, const float* __restrict__ fcb,
    const int* __restrict__ eos,
    float* __restrict__ idx_out, float* __restrict__ log_out,
    float* __restrict__ h, ushort_t* __restrict__ hhi, ushort_t* __restrict__ hlo,
    float* __restrict__ gi, float* __restrict__ gh, u64* __restrict__ partial,
    ushort_t* __restrict__ wihH, ushort_t* __restrict__ wihL,
    ushort_t* __restrict__ whhH, ushort_t* __restrict__ whhL,
    ushort_t* __restrict__ fcwH, ushort_t* __restrict__ fcwL)
{
  cg::grid_group grid = cg::this_grid();
  __shared__ ushort_t bhS[64][LP];
  __shared__ ushort_t blS[64][LP];
  __shared__ u64 scr[64][2];
  __shared__ u64 fin[64][4];
  __shared__ int idxS[64];
  const int bid = blockIdx.x, GRD = gridDim.x, tid = threadIdx.x;
  const int eosv = eos[0];

  prologue_body(seq, Wih, Whh, fcw, h, hhi, hlo,
                wihH, wihL, whhH, whhL, fcwH, fcwL);
  grid.sync();

  // pre-step: gh(h_0) + gi(emb[eos]) -> gates for step 0
  if (tid < 64) idxS[tid] = eosv;
  __syncthreads();
  for (int job = bid; job < 2 * NGH; job += GRD) {
    if (job < NGH) gh_job(job, hhi, hlo, whhH, whhL, gh, bhS, blS);
    else           gi_job(job - NGH, emb, idxS, wihH, wihL, gi, bhS, blS);
  }
  grid.sync();
  fuse_all(bid, GRD, gi, gh, bih, bhh, h, hhi, hlo);   // -> h_1
  grid.sync();

  for (int k = 0; k < T_STEPS; ++k) {
    // S1: logits(h_{k+1}) + sample partials  ||  gh(h_{k+1}) for next step
    const int njob = (k < T_STEPS - 1) ? (NT + NGH) : NT;
    for (int job = bid; job < njob; job += GRD) {
      if (job < NT) {
        f32x4 acc[2][2] = {};
        tile256<false>(bhS, blS, hhi, hlo, nullptr, nullptr, HH,
                       fcwH, fcwL, HH, job * 64, acc);
        sample_epi256(acc, scr, fcb, log_out + (size_t)k * BB * VV, job * 64,
                      partial, job, k);
      } else {
        gh_job(job - NT, hhi, hlo, whhH, whhL, gh, bhS, blS);
      }
    }
    grid.sync();

    // S2: reduce -> idx_k ; gi(emb[idx_k]) for next step
    if (bid < NGH) {
      reduce_idx(k, eosv, partial, fin, idxS, idx_out, bid == 0);
      if (k < T_STEPS - 1)
        gi_job(bid, emb, idxS, wihH, wihL, gi, bhS, blS);
    }
    if (k == T_STEPS - 1) break;
    grid.sync();

    // S3: fuse -> h_{k+2}
    fuse_all(bid, GRD, gi, gh, bih, bhh, h, hhi, hlo);
    grid.sync();
  }
}

// ---------------- multi-launch fallback (same device helpers) ----------------
__global__ __launch_bounds__(256) void k_pro(
    const float* seq, const float* Wih, const float* Whh, const float* fcw,
    float* h, ushort_t* hhi, ushort_t* hlo,
    ushort_t* wihH, ushort_t* wihL, ushort_t* whhH, ushort_t* whhL,
    ushort_t* fcwH, ushort_t* fcwL)
{
  prologue_body(seq, Wih, Whh, fcw, h, hhi, hlo,
                wihH, wihL, whhH, whhL, fcwH, fcwL);
}

__global__ __launch_bounds__(256, 4) void k_pre(
    const int* eos, const float* emb,
    const ushort_t* hhi, const ushort_t* hlo,
    const ushort_t* wihH, const ushort_t* wihL,
    const ushort_t* whhH, const ushort_t* whhL,
    float* gi, float* gh)
{
  __shared__ ushort_t bhS[64][LP];
  __shared__ ushort_t blS[64][LP];
  __shared__ int idxS[64];
  if (threadIdx.x < 64) idxS[threadIdx.x] = eos[0];
  __syncthreads();
  int job = blockIdx.x;
  if (job < NGH) gh_job(job, hhi, hlo, whhH, whhL, gh, bhS, blS);
  else           gi_job(job - NGH, emb, idxS, wihH, wihL, gi, bhS, blS);
}

__global__ __launch_bounds__(256) void k_fuse(
    const float* gi, const float* gh, const float* bih, const float* bhh,
    float* h, ushort_t* hhi, ushort_t* hlo)
{
  fuse_all(blockIdx.x, gridDim.x, gi, gh, bih, bhh, h, hhi, hlo);
}

__global__ __launch_bounds__(256, 4) void k_s1(
    int k, const ushort_t* hhi, const ushort_t* hlo,
    const ushort_t* fcwH, const ushort_t* fcwL, const float* fcb,
    const ushort_t* whhH, const ushort_t* whhL,
    float* log_out, float* gh, u64* partial)
{
  __shared__ ushort_t bhS[64][LP];
  __shared__ ushort_t blS[64][LP];
  __shared__ u64 scr[64][2];
  int job = blockIdx.x;
  if (job < NT) {
    f32x4 acc[2][2] = {};
    tile256<false>(bhS, blS, hhi, hlo, nullptr, nullptr, HH,
                   fcwH, fcwL, HH, job * 64, acc);
    sample_epi256(acc, scr, fcb, log_out + (size_t)k * BB * VV, job * 64,
                  partial, job, k);
  } else {
    gh_job(job - NT, hhi, hlo, whhH, whhL, gh, bhS, blS);
  }
}

__global__ __launch_bounds__(256, 4) void k_s2(
    int k, int doGi, const int* eos, const float* emb, const u64* partial,
    float* idx_out, const ushort_t* wihH, const ushort_t* wihL, float* gi)
{
  __shared__ ushort_t bhS[64][LP];
  __shared__ ushort_t blS[64][LP];
  __shared__ u64 fin[64][4];
  __shared__ int idxS[64];
  reduce_idx(k, eos[0], partial, fin, idxS, idx_out, blockIdx.x == 0);
  if (doGi)
    gi_job(blockIdx.x, emb, idxS, wihH, wihL, gi, bhS, blS);
}

extern "C" void kernel_launch(void* const* d_in, const int* in_sizes, int n_in,
                              void* d_out, int out_size, void* d_ws, size_t ws_size,
                              hipStream_t stream) {
  const float* seq = (const float*)d_in[0];
  const float* emb = (const float*)d_in[1];
  const float* Wih = (const float*)d_in[2];
  const float* Whh = (const float*)d_in[3];
  const float* bih = (const float*)d_in[4];
  const float* bhh = (const float*)d_in[5];
  const float* fcw = (const float*)d_in[6];
  const float* fcb = (const float*)d_in[7];
  const int*   eos = (const int*)d_in[8];

  float* out = (float*)d_out;
  float* idx_out = out;                              // [50][64] as float
  float* log_out = out + (size_t)T_STEPS * BB;       // [50][64][32000]

  uint8_t* wsp = (uint8_t*)d_ws;
  auto alloc = [&](size_t bytes) {
    uint8_t* p = wsp;
    wsp += (bytes + 255) & ~(size_t)255;
    return p;
  };
  float*    h    = (float*)alloc((size_t)BB * HH * 4);
  ushort_t* hhi  = (ushort_t*)alloc((size_t)BB * HH * 2);
  ushort_t* hlo  = (ushort_t*)alloc((size_t)BB * HH * 2);
  float*    gi   = (float*)alloc((size_t)BB * G3 * 4);
  float*    gh   = (float*)alloc((size_t)BB * G3 * 4);
  u64*      part = (u64*)alloc((size_t)NT * 64 * 8);
  ushort_t* wihH = (ushort_t*)alloc((size_t)G3 * DD * 2);
  ushort_t* wihL = (ushort_t*)alloc((size_t)G3 * DD * 2);
  ushort_t* whhH = (ushort_t*)alloc((size_t)G3 * HH * 2);
  ushort_t* whhL = (ushort_t*)alloc((size_t)G3 * HH * 2);
  ushort_t* fcwH = (ushort_t*)alloc((size_t)VV * HH * 2);
  ushort_t* fcwL = (ushort_t*)alloc((size_t)VV * HH * 2);

  // capture-safe device/occupancy queries -> legal cooperative grid
  int dev = 0;
  (void)hipGetDevice(&dev);
  int numCU = 0;
  (void)hipDeviceGetAttribute(&numCU, hipDeviceAttributeMultiprocessorCount, dev);
  int occ = 0;
  hipError_t qe = hipOccupancyMaxActiveBlocksPerMultiprocessor(
      &occ, reinterpret_cast<const void*>(&decoder_all), 256, 0);
  long grid = (qe == hipSuccess && numCU > 0) ? (long)occ * (long)numCU : 0;
  if (grid > NT + NGH) grid = NT + NGH;   // 548

  hipError_t err = hipErrorUnknown;
  if (grid >= 64) {
    void* args[] = {&seq, &emb, &Wih, &Whh, &bih, &bhh, &fcw, &fcb, &eos,
                    &idx_out, &log_out, &h, &hhi, &hlo, &gi, &gh, &part,
                    &wihH, &wihL, &whhH, &whhL, &fcwH, &fcwL};
    err = hipLaunchCooperativeKernel(reinterpret_cast<const void*>(&decoder_all),
                                     dim3((uint32_t)grid), dim3(256), args, 0, stream);
  }
  if (err != hipSuccess) {
    k_pro<<<512, 256, 0, stream>>>(seq, Wih, Whh, fcw, h, hhi, hlo,
                                   wihH, wihL, whhH, whhL, fcwH, fcwL);
    k_pre<<<2 * NGH, 256, 0, stream>>>(eos, emb, hhi, hlo, wihH, wihL,
                                       whhH, whhL, gi, gh);
    k_fuse<<<256, 256, 0, stream>>>(gi, gh, bih, bhh, h, hhi, hlo);
    for (int k = 0; k < T_STEPS; ++k) {
      int njob = (k < T_STEPS - 1) ? (NT + NGH) : NT;
      k_s1<<<njob, 256, 0, stream>>>(k, hhi, hlo, fcwH, fcwL, fcb,
                                     whhH, whhL, log_out, gh, part);
      k_s2<<<NGH, 256, 0, stream>>>(k, (k < T_STEPS - 1) ? 1 : 0, eos, emb,
                                    part, idx_out, wihH, wihL, gi);
      if (k < T_STEPS - 1)
        k_fuse<<<256, 256, 0, stream>>>(gi, gh, bih, bhh, h, hhi, hlo);
    }
  }
}

// Round 8
// 14849.416 us; speedup vs baseline: 1.0045x; 1.0045x over previous
//
#include <hip/hip_runtime.h>
#include <hip/hip_cooperative_groups.h>
#include <stdint.h>

namespace cg = cooperative_groups;

#define BB 64
#define DD 512
#define HH 1024
#define VV 32000
#define T_STEPS 50
#define G3 3072
#define NT 500      // logits col-tiles (64 cols each)
#define NGH 48      // gate col-tiles (64 cols each)
#define NS2 16      // S2 mega-blocks (each: reduce + 3 gi tiles + fuse slice)
#define LP 42       // LDS row stride (ushorts): 21 dwords, gcd(21,32)=1

typedef __attribute__((ext_vector_type(8))) short bf16x8;
typedef __attribute__((ext_vector_type(4))) float f32x4;
typedef unsigned long long u64;
typedef unsigned short ushort_t;

__device__ __forceinline__ uint32_t rotl32(uint32_t x, int d) {
  return (x << d) | (x >> (32 - d));
}

// JAX threefry2x32 (20 rounds) — verified exact in rounds 1-7.
__device__ __forceinline__ void threefry2x32(uint32_t k0, uint32_t k1,
                                             uint32_t& x0, uint32_t& x1) {
  uint32_t ks0 = k0, ks1 = k1, ks2 = k0 ^ k1 ^ 0x1BD11BDAu;
  x0 += ks0; x1 += ks1;
#define TF_R(r) { x0 += x1; x1 = rotl32(x1, (r)); x1 ^= x0; }
  TF_R(13) TF_R(15) TF_R(26) TF_R(6)
  x0 += ks1; x1 += ks2 + 1u;
  TF_R(17) TF_R(29) TF_R(16) TF_R(24)
  x0 += ks2; x1 += ks0 + 2u;
  TF_R(13) TF_R(15) TF_R(26) TF_R(6)
  x0 += ks0; x1 += ks1 + 3u;
  TF_R(17) TF_R(29) TF_R(16) TF_R(24)
  x0 += ks1; x1 += ks2 + 4u;
  TF_R(13) TF_R(15) TF_R(26) TF_R(6)
  x0 += ks2; x1 += ks0 + 5u;
#undef TF_R
}

__device__ __forceinline__ uint32_t f2bf(float f) {
  uint32_t u = __float_as_uint(f);
  return (u + 0x7fffu + ((u >> 16) & 1u)) >> 16;
}
__device__ __forceinline__ float bf2f(uint32_t b) { return __uint_as_float(b << 16); }

__device__ __forceinline__ u64 packkey(float v, int c) {
  uint32_t s = __float_as_uint(v);
  uint32_t mo = (s & 0x80000000u) ? ~s : (s | 0x80000000u);
  return ((u64)mo << 32) | (uint32_t)(~(uint32_t)c);
}
__device__ __forceinline__ u64 umax64(u64 a, u64 b) { return a > b ? a : b; }

union BF8 { uint32_t u[4]; bf16x8 v; };

__device__ __forceinline__ void split8(const float* f, bf16x8& hi, bf16x8& lo) {
  BF8 H, L;
#pragma unroll
  for (int i = 0; i < 4; ++i) {
    float a = f[2 * i], b = f[2 * i + 1];
    uint32_t ha = f2bf(a), hb = f2bf(b);
    float ra = a - bf2f(ha), rb = b - bf2f(hb);
    H.u[i] = ha | (hb << 16);
    L.u[i] = f2bf(ra) | (f2bf(rb) << 16);
  }
  hi = H.v; lo = L.v;
}

__device__ __forceinline__ void split_store4(const float4 v, ushort_t* hi,
                                             ushort_t* lo, long i) {
  uint32_t h0 = f2bf(v.x), h1 = f2bf(v.y), h2 = f2bf(v.z), h3 = f2bf(v.w);
  uint32_t l0 = f2bf(v.x - bf2f(h0)), l1 = f2bf(v.y - bf2f(h1));
  uint32_t l2 = f2bf(v.z - bf2f(h2)), l3 = f2bf(v.w - bf2f(h3));
  *(uint2*)(hi + i) = make_uint2(h0 | (h1 << 16), h2 | (h3 << 16));
  *(uint2*)(lo + i) = make_uint2(l0 | (l1 << 16), l2 | (l3 << 16));
}

__device__ void split_arr(const float* __restrict__ s, ushort_t* __restrict__ hi,
                          ushort_t* __restrict__ lo, long n, long st, long stride) {
  for (long i = st; i < n; i += stride) {
    float4 v = *(const float4*)(s + i);
    split_store4(v, hi, lo, i);
  }
}

// 256-thread 64x64 tile with 1-deep register prefetch of A and B fragments.
// B: pre-split bf16 hi/lo, staged via LDS (padded [64][LP]). A: pre-split bf16
// rows or fp32 rows gathered via rowidx (AGATHER). 3-term split MFMA (proven).
template<bool AGATHER>
__device__ __forceinline__ void tile256(
    ushort_t (*__restrict__ bhS)[LP], ushort_t (*__restrict__ blS)[LP],
    const ushort_t* __restrict__ Ahi, const ushort_t* __restrict__ Alo,
    const float* __restrict__ Ag, const int* __restrict__ rowidx, int lda,
    const ushort_t* __restrict__ Bhi, const ushort_t* __restrict__ Blo,
    int K, int n0, f32x4 acc[2][2])
{
  const int tid = threadIdx.x, lane = tid & 63, w = tid >> 6;
  const int l15 = lane & 15, q = lane >> 4;
  const int rw = (w >> 1) * 32, cw = (w & 1) * 32;
  const int srow = tid >> 2, schunk = (tid & 3) * 8;

  size_t abase[2];
#pragma unroll
  for (int m = 0; m < 2; ++m) {
    int r = rw + 16 * m + l15;
    abase[m] = (size_t)(AGATHER ? rowidx[r] : r) * lda + 8 * q;
  }
  const size_t bstage = (size_t)(n0 + srow) * K + schunk;

  // ---- prefetch iteration 0 ----
  bf16x8 pbh = *(const bf16x8*)(Bhi + bstage);
  bf16x8 pbl = *(const bf16x8*)(Blo + bstage);
  bf16x8 pah[2], pal[2];
  float4 pga0[2], pga1[2];
#pragma unroll
  for (int m = 0; m < 2; ++m) {
    if constexpr (AGATHER) {
      pga0[m] = *(const float4*)(Ag + abase[m]);
      pga1[m] = *(const float4*)(Ag + abase[m] + 4);
    } else {
      pah[m] = *(const bf16x8*)(Ahi + abase[m]);
      pal[m] = *(const bf16x8*)(Alo + abase[m]);
    }
  }

  for (int k0 = 0; k0 < K; k0 += 32) {
    __syncthreads();                      // prior LDS reads complete
    *(bf16x8*)&bhS[srow][schunk] = pbh;   // consume B prefetch
    *(bf16x8*)&blS[srow][schunk] = pbl;

    bf16x8 ah[2], al[2];
#pragma unroll
    for (int m = 0; m < 2; ++m) {
      if constexpr (AGATHER) {
        float f[8] = {pga0[m].x, pga0[m].y, pga0[m].z, pga0[m].w,
                      pga1[m].x, pga1[m].y, pga1[m].z, pga1[m].w};
        split8(f, ah[m], al[m]);
      } else {
        ah[m] = pah[m];
        al[m] = pal[m];
      }
    }

    // ---- issue next iteration's loads (overlap with MFMA phase) ----
    const int kn = (k0 + 32 < K) ? (k0 + 32) : 0;
    pbh = *(const bf16x8*)(Bhi + bstage + kn);
    pbl = *(const bf16x8*)(Blo + bstage + kn);
#pragma unroll
    for (int m = 0; m < 2; ++m) {
      if constexpr (AGATHER) {
        pga0[m] = *(const float4*)(Ag + abase[m] + kn);
        pga1[m] = *(const float4*)(Ag + abase[m] + kn + 4);
      } else {
        pah[m] = *(const bf16x8*)(Ahi + abase[m] + kn);
        pal[m] = *(const bf16x8*)(Alo + abase[m] + kn);
      }
    }
    __syncthreads();                      // staging visible

    bf16x8 bhf[2], blf[2];
#pragma unroll
    for (int n = 0; n < 2; ++n) {
      bhf[n] = *(const bf16x8*)&bhS[cw + 16 * n + l15][8 * q];
      blf[n] = *(const bf16x8*)&blS[cw + 16 * n + l15][8 * q];
    }
#pragma unroll
    for (int m = 0; m < 2; ++m)
#pragma unroll
      for (int n = 0; n < 2; ++n) {
        acc[m][n] = __builtin_amdgcn_mfma_f32_16x16x32_bf16(ah[m], bhf[n], acc[m][n], 0, 0, 0);
        acc[m][n] = __builtin_amdgcn_mfma_f32_16x16x32_bf16(ah[m], blf[n], acc[m][n], 0, 0, 0);
        acc[m][n] = __builtin_amdgcn_mfma_f32_16x16x32_bf16(al[m], bhf[n], acc[m][n], 0, 0, 0);
      }
  }
}

__device__ __forceinline__ void store_tile256(f32x4 acc[2][2], float* __restrict__ C,
                                              int ldc, int n0)
{
  const int tid = threadIdx.x, lane = tid & 63, w = tid >> 6;
  const int l15 = lane & 15, q = lane >> 4;
  const int rw = (w >> 1) * 32, cw = (w & 1) * 32;
#pragma unroll
  for (int m = 0; m < 2; ++m)
#pragma unroll
    for (int n = 0; n < 2; ++n)
#pragma unroll
      for (int r = 0; r < 4; ++r)
        C[(size_t)(rw + 16 * m + 4 * q + r) * ldc + n0 + cw + 16 * n + l15] = acc[m][n][r];
}

// logits store(+bias, nontemporal) + fused gumbel-argmax partial (proven math)
__device__ __forceinline__ void sample_epi256(
    f32x4 acc[2][2], u64 (*__restrict__ scr)[2],
    const float* __restrict__ bias, float* __restrict__ C, int n0,
    u64* __restrict__ partial, int job, int t)
{
  const int tid = threadIdx.x, lane = tid & 63, w = tid >> 6;
  const int l15 = lane & 15, q = lane >> 4;
  const int rw = (w >> 1) * 32, cw = (w & 1) * 32;

  uint32_t kt0 = 0u, kt1 = (uint32_t)t;
  threefry2x32(0u, 42u, kt0, kt1);

  u64 bk[2][4];
#pragma unroll
  for (int m = 0; m < 2; ++m)
#pragma unroll
    for (int r = 0; r < 4; ++r) bk[m][r] = 0ull;

#pragma unroll
  for (int m = 0; m < 2; ++m)
#pragma unroll
    for (int n = 0; n < 2; ++n)
#pragma unroll
      for (int r = 0; r < 4; ++r) {
        int row = rw + 16 * m + 4 * q + r;          // batch index
        int col = n0 + cw + 16 * n + l15;           // vocab index
        float val = acc[m][n][r] + bias[col];
        __builtin_nontemporal_store(val, &C[(size_t)row * VV + col]);
        uint32_t c0 = 0u, c1 = (uint32_t)(row * VV + col);
        threefry2x32(kt0, kt1, c0, c1);
        uint32_t bits = c0 ^ c1;
        float u = __uint_as_float((bits >> 9) | 0x3f800000u) - 1.0f;
        if (u == 0.0f) u = 1.17549435e-38f;
        float g = -__logf(-__logf(u));
        bk[m][r] = umax64(bk[m][r], packkey(val + g, col));
      }
#pragma unroll
  for (int off = 1; off < 16; off <<= 1)
#pragma unroll
    for (int m = 0; m < 2; ++m)
#pragma unroll
      for (int r = 0; r < 4; ++r)
        bk[m][r] = umax64(bk[m][r], (u64)__shfl_xor((long long)bk[m][r], off, 64));

  if (l15 == 0) {
#pragma unroll
    for (int m = 0; m < 2; ++m)
#pragma unroll
      for (int r = 0; r < 4; ++r)
        scr[rw + 16 * m + 4 * q + r][w & 1] = bk[m][r];
  }
  __syncthreads();
  if (tid < 64)
    partial[(size_t)job * 64 + tid] = umax64(scr[tid][0], scr[tid][1]);
  __syncthreads();
}

// block-local: reduce partial[500][64] -> idxS[64]
__device__ __forceinline__ void reduce_idx(
    int k, int eosv, const u64* __restrict__ partial,
    u64 (*__restrict__ fin)[4], int* __restrict__ idxS,
    float* __restrict__ idx_out, bool writeOut)
{
  const int tid = threadIdx.x;
  if (k < 0) {
    if (tid < 64) idxS[tid] = eosv;
    __syncthreads();
    return;
  }
  const int row = tid & 63, sub = tid >> 6;
  u64 best = 0;
  for (int i = sub; i < NT; i += 4)
    best = umax64(best, partial[(size_t)i * 64 + row]);
  fin[row][sub] = best;
  __syncthreads();
  if (tid < 64) {
    u64 b = umax64(umax64(fin[tid][0], fin[tid][1]),
                   umax64(fin[tid][2], fin[tid][3]));
    int idx = (int)(~(uint32_t)b);
    idxS[tid] = idx;
    if (writeOut) idx_out[(size_t)k * BB + tid] = (float)idx;
  }
  __syncthreads();
}

__device__ __forceinline__ void gh_job(
    int g, const ushort_t* __restrict__ hhi, const ushort_t* __restrict__ hlo,
    const ushort_t* __restrict__ whhH, const ushort_t* __restrict__ whhL,
    float* __restrict__ gh,
    ushort_t (*__restrict__ bhS)[LP], ushort_t (*__restrict__ blS)[LP])
{
  f32x4 acc[2][2] = {};
  tile256<false>(bhS, blS, hhi, hlo, nullptr, nullptr, HH, whhH, whhL, HH, g * 64, acc);
  store_tile256(acc, gh, G3, g * 64);
}

__device__ __forceinline__ void gi_job(
    int g, const float* __restrict__ emb, const int* __restrict__ idxS,
    const ushort_t* __restrict__ wihH, const ushort_t* __restrict__ wihL,
    float* __restrict__ gi,
    ushort_t (*__restrict__ bhS)[LP], ushort_t (*__restrict__ blS)[LP])
{
  f32x4 acc[2][2] = {};
  tile256<true>(bhS, blS, nullptr, nullptr, emb, idxS, DD, wihH, wihL, DD, g * 64, acc);
  store_tile256(acc, gi, G3, g * 64);
}

__device__ __forceinline__ void gru_math(
    const float* __restrict__ gir, const float* __restrict__ ghr,
    const float* __restrict__ bih, const float* __restrict__ bhh,
    float* __restrict__ h, ushort_t* __restrict__ hhi, ushort_t* __restrict__ hlo,
    int b, int j)
{
  float ir  = gir[j]        + bih[j],        hr = ghr[j]        + bhh[j];
  float iz  = gir[j + 1024] + bih[j + 1024], hz = ghr[j + 1024] + bhh[j + 1024];
  float in_ = gir[j + 2048] + bih[j + 2048], hn = ghr[j + 2048] + bhh[j + 2048];
  float r = 1.f / (1.f + expf(-(ir + hr)));
  float z = 1.f / (1.f + expf(-(iz + hz)));
  float n = tanhf(in_ + r * hn);
  int i = b * HH + j;
  float hv = (1.f - z) * n + z * h[i];
  h[i] = hv;
  uint32_t hb = f2bf(hv);
  hhi[i] = (ushort_t)hb;
  hlo[i] = (ushort_t)f2bf(hv - bf2f(hb));
}

__device__ __forceinline__ void fuse_all(
    int bid, int GRD,
    const float* __restrict__ gi, const float* __restrict__ gh,
    const float* __restrict__ bih, const float* __restrict__ bhh,
    float* __restrict__ h, ushort_t* __restrict__ hhi, ushort_t* __restrict__ hlo)
{
  for (int i = bid * 256 + threadIdx.x; i < BB * HH; i += GRD * 256) {
    int b = i >> 10, j = i & 1023;
    gru_math(gi + (size_t)b * G3, gh + (size_t)b * G3, bih, bhh, h, hhi, hlo, b, j);
  }
}

__device__ __forceinline__ void fuse_slice(
    int mb, const float* __restrict__ gi, const float* __restrict__ gh,
    const float* __restrict__ bih, const float* __restrict__ bhh,
    float* __restrict__ h, ushort_t* __restrict__ hhi, ushort_t* __restrict__ hlo)
{
  for (int e = threadIdx.x; e < 64 * 64; e += 256) {
    int b = e >> 6, j = mb * 64 + (e & 63);
    gru_math(gi + (size_t)b * G3, gh + (size_t)b * G3, bih, bhh, h, hhi, hlo, b, j);
  }
}

// S2 mega-block: reduce -> idx; 3 gi tiles {mb, mb+16, mb+32}; local fuse.
__device__ __forceinline__ void s2_body(
    int mb, int k, int eosv, const float* __restrict__ emb,
    const float* __restrict__ bih, const float* __restrict__ bhh,
    float* __restrict__ idx_out, const u64* __restrict__ partial,
    const ushort_t* __restrict__ wihH, const ushort_t* __restrict__ wihL,
    float* __restrict__ gi, const float* __restrict__ gh,
    float* __restrict__ h, ushort_t* __restrict__ hhi, ushort_t* __restrict__ hlo,
    ushort_t (*__restrict__ bhS)[LP], ushort_t (*__restrict__ blS)[LP],
    u64 (*__restrict__ fin)[4], int* __restrict__ idxS)
{
  reduce_idx(k, eosv, partial, fin, idxS, idx_out, mb == 0);
  if (k >= T_STEPS - 1) return;
#pragma unroll
  for (int g3 = 0; g3 < 3; ++g3)
    gi_job(mb + 16 * g3, emb, idxS, wihH, wihL, gi, bhS, blS);
  __threadfence_block();
  __syncthreads();
  fuse_slice(mb, gi, gh, bih, bhh, h, hhi, hlo);
}

__device__ __forceinline__ void prologue_body(
    const float* __restrict__ seq, const float* __restrict__ Wih,
    const float* __restrict__ Whh, const float* __restrict__ fcw,
    float* __restrict__ h0, ushort_t* __restrict__ h0hi, ushort_t* __restrict__ h0lo,
    ushort_t* __restrict__ wihH, ushort_t* __restrict__ wihL,
    ushort_t* __restrict__ whhH, ushort_t* __restrict__ whhL,
    ushort_t* __restrict__ fcwH, ushort_t* __restrict__ fcwL)
{
  long st = 4L * ((long)blockIdx.x * blockDim.x + threadIdx.x);
  long stride = 4L * (long)gridDim.x * blockDim.x;
  split_arr(Wih, wihH, wihL, (long)G3 * DD, st, stride);
  split_arr(Whh, whhH, whhL, (long)G3 * HH, st, stride);
  split_arr(fcw, fcwH, fcwL, (long)VV * HH, st, stride);
  for (long i = st; i < BB * HH; i += stride) {
    float4 v = *(const float4*)(seq + i);
    *(float4*)(h0 + i) = v;
    split_store4(v, h0hi, h0lo, i);
  }
}

// ---------------- cooperative mega-kernel (2 syncs/step) ----------------
__global__ __launch_bounds__(256, 4) void decoder_all(
    const float* __restrict__ seq, const float* __restrict__ emb,
    const float* __restrict__ Wih, const float* __restrict__ Whh,
    const float* __restrict__ bih, const float* __restrict__ bhh,
    const float* __restrict__ fcw, const float* __restrict__ fcb,
    const int* __restrict__ eos,
    float* __restrict__ idx_out, float* __restrict__ log_out,
    float* __restrict__ h, ushort_t* __restrict__ hhi, ushort_t* __restrict__ hlo,
    float* __restrict__ gi, float* __restrict__ gh, u64* __restrict__ partial,
    ushort_t* __restrict__ wihH, ushort_t* __restrict__ wihL,
    ushort_t* __restrict__ whhH, ushort_t* __restrict__ whhL,
    ushort_t* __restrict__ fcwH, ushort_t* __restrict__ fcwL)
{
  cg::grid_group grid = cg::this_grid();
  __shared__ ushort_t bhS[64][LP];
  __shared__ ushort_t blS[64][LP];
  __shared__ u64 scr[64][2];
  __shared__ u64 fin[64][4];
  __shared__ int idxS[64];
  const int bid = blockIdx.x, GRD = gridDim.x, tid = threadIdx.x;
  const int eosv = eos[0];

  prologue_body(seq, Wih, Whh, fcw, h, hhi, hlo,
                wihH, wihL, whhH, whhL, fcwH, fcwL);
  grid.sync();

  // pre-step: gh(h_0) || gi(emb[eos]); fuse -> h_1
  if (tid < 64) idxS[tid] = eosv;
  __syncthreads();
  for (int job = bid; job < 2 * NGH; job += GRD) {
    if (job < NGH) gh_job(job, hhi, hlo, whhH, whhL, gh, bhS, blS);
    else           gi_job(job - NGH, emb, idxS, wihH, wihL, gi, bhS, blS);
  }
  grid.sync();
  fuse_all(bid, GRD, gi, gh, bih, bhh, h, hhi, hlo);   // -> h_1
  grid.sync();

  for (int k = 0; k < T_STEPS; ++k) {
    // S1: logits(h_{k+1}) + partials  ||  gh(h_{k+1})
    const int njob = (k < T_STEPS - 1) ? (NT + NGH) : NT;
    for (int job = bid; job < njob; job += GRD) {
      if (job < NT) {
        f32x4 acc[2][2] = {};
        tile256<false>(bhS, blS, hhi, hlo, nullptr, nullptr, HH,
                       fcwH, fcwL, HH, job * 64, acc);
        sample_epi256(acc, scr, fcb, log_out + (size_t)k * BB * VV, job * 64,
                      partial, job, k);
      } else {
        gh_job(job - NT, hhi, hlo, whhH, whhL, gh, bhS, blS);
      }
    }
    grid.sync();

    // S2: reduce -> idx_k; gi(emb[idx_k]); local fuse -> h_{k+2}
    if (bid < NS2)
      s2_body(bid, k, eosv, emb, bih, bhh, idx_out, partial,
              wihH, wihL, gi, gh, h, hhi, hlo, bhS, blS, fin, idxS);
    if (k == T_STEPS - 1) break;
    grid.sync();
  }
}

// ---------------- multi-launch fallback (same device helpers) ----------------
__global__ __launch_bounds__(256) void k_pro(
    const float* seq, const float* Wih, const float* Whh, const float* fcw,
    float* h, ushort_t* hhi, ushort_t* hlo,
    ushort_t* wihH, ushort_t* wihL, ushort_t* whhH, ushort_t* whhL,
    ushort_t* fcwH, ushort_t* fcwL)
{
  prologue_body(seq, Wih, Whh, fcw, h, hhi, hlo,
                wihH, wihL, whhH, whhL, fcwH, fcwL);
}

__global__ __launch_bounds__(256, 4) void k_pre(
    const int* eos, const float* emb,
    const ushort_t* hhi, const ushort_t* hlo,
    const ushort_t* wihH, const ushort_t* wihL,
    const ushort_t* whhH, const ushort_t* whhL,
    float* gi, float* gh)
{
  __shared__ ushort_t bhS[64][LP];
  __shared__ ushort_t blS[64][LP];
  __shared__ int idxS[64];
  if (threadIdx.x < 64) idxS[threadIdx.x] = eos[0];
  __syncthreads();
  int job = blockIdx.x;
  if (job < NGH) gh_job(job, hhi, hlo, whhH, whhL, gh, bhS, blS);
  else           gi_job(job - NGH, emb, idxS, wihH, wihL, gi, bhS, blS);
}

__global__ __launch_bounds__(256) void k_fuse(
    const float* gi, const float* gh, const float* bih, const float* bhh,
    float* h, ushort_t* hhi, ushort_t* hlo)
{
  fuse_all(blockIdx.x, gridDim.x, gi, gh, bih, bhh, h, hhi, hlo);
}

__global__ __launch_bounds__(256, 4) void k_s1(
    int k, const ushort_t* hhi, const ushort_t* hlo,
    const ushort_t* fcwH, const ushort_t* fcwL, const float* fcb,
    const ushort_t* whhH, const ushort_t* whhL,
    float* log_out, float* gh, u64* partial)
{
  __shared__ ushort_t bhS[64][LP];
  __shared__ ushort_t blS[64][LP];
  __shared__ u64 scr[64][2];
  int job = blockIdx.x;
  if (job < NT) {
    f32x4 acc[2][2] = {};
    tile256<false>(bhS, blS, hhi, hlo, nullptr, nullptr, HH,
                   fcwH, fcwL, HH, job * 64, acc);
    sample_epi256(acc, scr, fcb, log_out + (size_t)k * BB * VV, job * 64,
                  partial, job, k);
  } else {
    gh_job(job - NT, hhi, hlo, whhH, whhL, gh, bhS, blS);
  }
}

__global__ __launch_bounds__(256, 4) void k_s2(
    int k, const int* eos, const float* emb,
    const float* bih, const float* bhh, float* idx_out, const u64* partial,
    const ushort_t* wihH, const ushort_t* wihL,
    float* gi, const float* gh,
    float* h, ushort_t* hhi, ushort_t* hlo)
{
  __shared__ ushort_t bhS[64][LP];
  __shared__ ushort_t blS[64][LP];
  __shared__ u64 fin[64][4];
  __shared__ int idxS[64];
  s2_body(blockIdx.x, k, eos[0], emb, bih, bhh, idx_out, partial,
          wihH, wihL, gi, gh, h, hhi, hlo, bhS, blS, fin, idxS);
}

extern "C" void kernel_launch(void* const* d_in, const int* in_sizes, int n_in,
                              void* d_out, int out_size, void* d_ws, size_t ws_size,
                              hipStream_t stream) {
  const float* seq = (const float*)d_in[0];
  const float* emb = (const float*)d_in[1];
  const float* Wih = (const float*)d_in[2];
  const float* Whh = (const float*)d_in[3];
  const float* bih = (const float*)d_in[4];
  const float* bhh = (const float*)d_in[5];
  const float* fcw = (const float*)d_in[6];
  const float* fcb = (const float*)d_in[7];
  const int*   eos = (const int*)d_in[8];

  float* out = (float*)d_out;
  float* idx_out = out;                              // [50][64] as float
  float* log_out = out + (size_t)T_STEPS * BB;       // [50][64][32000]

  uint8_t* wsp = (uint8_t*)d_ws;
  auto alloc = [&](size_t bytes) {
    uint8_t* p = wsp;
    wsp += (bytes + 255) & ~(size_t)255;
    return p;
  };
  float*    h    = (float*)alloc((size_t)BB * HH * 4);
  ushort_t* hhi  = (ushort_t*)alloc((size_t)BB * HH * 2);
  ushort_t* hlo  = (ushort_t*)alloc((size_t)BB * HH * 2);
  float*    gi   = (float*)alloc((size_t)BB * G3 * 4);
  float*    gh   = (float*)alloc((size_t)BB * G3 * 4);
  u64*      part = (u64*)alloc((size_t)NT * 64 * 8);
  ushort_t* wihH = (ushort_t*)alloc((size_t)G3 * DD * 2);
  ushort_t* wihL = (ushort_t*)alloc((size_t)G3 * DD * 2);
  ushort_t* whhH = (ushort_t*)alloc((size_t)G3 * HH * 2);
  ushort_t* whhL = (ushort_t*)alloc((size_t)G3 * HH * 2);
  ushort_t* fcwH = (ushort_t*)alloc((size_t)VV * HH * 2);
  ushort_t* fcwL = (ushort_t*)alloc((size_t)VV * HH * 2);

  // capture-safe device/occupancy queries -> legal cooperative grid
  int dev = 0;
  (void)hipGetDevice(&dev);
  int numCU = 0;
  (void)hipDeviceGetAttribute(&numCU, hipDeviceAttributeMultiprocessorCount, dev);
  int occ = 0;
  hipError_t qe = hipOccupancyMaxActiveBlocksPerMultiprocessor(
      &occ, reinterpret_cast<const void*>(&decoder_all), 256, 0);
  long grid = (qe == hipSuccess && numCU > 0) ? (long)occ * (long)numCU : 0;
  if (grid > NT + NGH) grid = NT + NGH;   // 548

  hipError_t err = hipErrorUnknown;
  if (grid >= 64) {
    void* args[] = {&seq, &emb, &Wih, &Whh, &bih, &bhh, &fcw, &fcb, &eos,
                    &idx_out, &log_out, &h, &hhi, &hlo, &gi, &gh, &part,
                    &wihH, &wihL, &whhH, &whhL, &fcwH, &fcwL};
    err = hipLaunchCooperativeKernel(reinterpret_cast<const void*>(&decoder_all),
                                     dim3((uint32_t)grid), dim3(256), args, 0, stream);
  }
  if (err != hipSuccess) {
    k_pro<<<512, 256, 0, stream>>>(seq, Wih, Whh, fcw, h, hhi, hlo,
                                   wihH, wihL, whhH, whhL, fcwH, fcwL);
    k_pre<<<2 * NGH, 256, 0, stream>>>(eos, emb, hhi, hlo, wihH, wihL,
                                       whhH, whhL, gi, gh);
    k_fuse<<<256, 256, 0, stream>>>(gi, gh, bih, bhh, h, hhi, hlo);
    for (int k = 0; k < T_STEPS; ++k) {
      int njob = (k < T_STEPS - 1) ? (NT + NGH) : NT;
      k_s1<<<njob, 256, 0, stream>>>(k, hhi, hlo, fcwH, fcwL, fcb,
                                     whhH, whhL, log_out, gh, part);
      k_s2<<<NS2, 256, 0, stream>>>(k, eos, emb, bih, bhh, idx_out, part,
                                    wihH, wihL, gi, gh, h, hhi, hlo);
    }
  }
}

// Round 9
// 8186.624 us; speedup vs baseline: 1.8221x; 1.8139x over previous
//
#include <hip/hip_runtime.h>
#include <stdint.h>

#define BB 64
#define DD 512
#define HH 1024
#define VV 32000
#define T_STEPS 50
#define G3 3072
#define NT 500      // logits col-tiles (64 cols each)
#define NGH 48      // gate col-tiles (64 cols each)
#define NS2 16      // S2 mega-blocks (each: reduce + 3 gi tiles + fuse slice)
#define LP 42       // LDS row stride (ushorts): 21 dwords, gcd(21,32)=1

typedef __attribute__((ext_vector_type(8))) short bf16x8;
typedef __attribute__((ext_vector_type(4))) float f32x4;
typedef unsigned long long u64;
typedef unsigned short ushort_t;

__device__ __forceinline__ uint32_t rotl32(uint32_t x, int d) {
  return (x << d) | (x >> (32 - d));
}

// JAX threefry2x32 (20 rounds) — verified exact in rounds 1-8.
__device__ __forceinline__ void threefry2x32(uint32_t k0, uint32_t k1,
                                             uint32_t& x0, uint32_t& x1) {
  uint32_t ks0 = k0, ks1 = k1, ks2 = k0 ^ k1 ^ 0x1BD11BDAu;
  x0 += ks0; x1 += ks1;
#define TF_R(r) { x0 += x1; x1 = rotl32(x1, (r)); x1 ^= x0; }
  TF_R(13) TF_R(15) TF_R(26) TF_R(6)
  x0 += ks1; x1 += ks2 + 1u;
  TF_R(17) TF_R(29) TF_R(16) TF_R(24)
  x0 += ks2; x1 += ks0 + 2u;
  TF_R(13) TF_R(15) TF_R(26) TF_R(6)
  x0 += ks0; x1 += ks1 + 3u;
  TF_R(17) TF_R(29) TF_R(16) TF_R(24)
  x0 += ks1; x1 += ks2 + 4u;
  TF_R(13) TF_R(15) TF_R(26) TF_R(6)
  x0 += ks2; x1 += ks0 + 5u;
#undef TF_R
}

__device__ __forceinline__ uint32_t f2bf(float f) {
  uint32_t u = __float_as_uint(f);
  return (u + 0x7fffu + ((u >> 16) & 1u)) >> 16;
}
__device__ __forceinline__ float bf2f(uint32_t b) { return __uint_as_float(b << 16); }

__device__ __forceinline__ u64 packkey(float v, int c) {
  uint32_t s = __float_as_uint(v);
  uint32_t mo = (s & 0x80000000u) ? ~s : (s | 0x80000000u);
  return ((u64)mo << 32) | (uint32_t)(~(uint32_t)c);
}
__device__ __forceinline__ u64 umax64(u64 a, u64 b) { return a > b ? a : b; }

union BF8 { uint32_t u[4]; bf16x8 v; };

__device__ __forceinline__ void split8(const float* f, bf16x8& hi, bf16x8& lo) {
  BF8 H, L;
#pragma unroll
  for (int i = 0; i < 4; ++i) {
    float a = f[2 * i], b = f[2 * i + 1];
    uint32_t ha = f2bf(a), hb = f2bf(b);
    float ra = a - bf2f(ha), rb = b - bf2f(hb);
    H.u[i] = ha | (hb << 16);
    L.u[i] = f2bf(ra) | (f2bf(rb) << 16);
  }
  hi = H.v; lo = L.v;
}

__device__ __forceinline__ void split_store4(const float4 v, ushort_t* hi,
                                             ushort_t* lo, long i) {
  uint32_t h0 = f2bf(v.x), h1 = f2bf(v.y), h2 = f2bf(v.z), h3 = f2bf(v.w);
  uint32_t l0 = f2bf(v.x - bf2f(h0)), l1 = f2bf(v.y - bf2f(h1));
  uint32_t l2 = f2bf(v.z - bf2f(h2)), l3 = f2bf(v.w - bf2f(h3));
  *(uint2*)(hi + i) = make_uint2(h0 | (h1 << 16), h2 | (h3 << 16));
  *(uint2*)(lo + i) = make_uint2(l0 | (l1 << 16), l2 | (l3 << 16));
}

__device__ void split_arr(const float* __restrict__ s, ushort_t* __restrict__ hi,
                          ushort_t* __restrict__ lo, long n, long st, long stride) {
  for (long i = st; i < n; i += stride) {
    float4 v = *(const float4*)(s + i);
    split_store4(v, hi, lo, i);
  }
}

// 256-thread 64x64 tile, 1-deep register prefetch, LDS-staged B (bf16 hi/lo,
// padded [64][LP]), 2x2 wave quadrants, 3-term split-precision MFMA (proven).
template<bool AGATHER>
__device__ __forceinline__ void tile256(
    ushort_t (*__restrict__ bhS)[LP], ushort_t (*__restrict__ blS)[LP],
    const ushort_t* __restrict__ Ahi, const ushort_t* __restrict__ Alo,
    const float* __restrict__ Ag, const int* __restrict__ rowidx, int lda,
    const ushort_t* __restrict__ Bhi, const ushort_t* __restrict__ Blo,
    int K, int n0, f32x4 acc[2][2])
{
  const int tid = threadIdx.x, lane = tid & 63, w = tid >> 6;
  const int l15 = lane & 15, q = lane >> 4;
  const int rw = (w >> 1) * 32, cw = (w & 1) * 32;
  const int srow = tid >> 2, schunk = (tid & 3) * 8;

  size_t abase[2];
#pragma unroll
  for (int m = 0; m < 2; ++m) {
    int r = rw + 16 * m + l15;
    abase[m] = (size_t)(AGATHER ? rowidx[r] : r) * lda + 8 * q;
  }
  const size_t bstage = (size_t)(n0 + srow) * K + schunk;

  bf16x8 pbh = *(const bf16x8*)(Bhi + bstage);
  bf16x8 pbl = *(const bf16x8*)(Blo + bstage);
  bf16x8 pah[2], pal[2];
  float4 pga0[2], pga1[2];
#pragma unroll
  for (int m = 0; m < 2; ++m) {
    if constexpr (AGATHER) {
      pga0[m] = *(const float4*)(Ag + abase[m]);
      pga1[m] = *(const float4*)(Ag + abase[m] + 4);
    } else {
      pah[m] = *(const bf16x8*)(Ahi + abase[m]);
      pal[m] = *(const bf16x8*)(Alo + abase[m]);
    }
  }

  for (int k0 = 0; k0 < K; k0 += 32) {
    __syncthreads();
    *(bf16x8*)&bhS[srow][schunk] = pbh;
    *(bf16x8*)&blS[srow][schunk] = pbl;

    bf16x8 ah[2], al[2];
#pragma unroll
    for (int m = 0; m < 2; ++m) {
      if constexpr (AGATHER) {
        float f[8] = {pga0[m].x, pga0[m].y, pga0[m].z, pga0[m].w,
                      pga1[m].x, pga1[m].y, pga1[m].z, pga1[m].w};
        split8(f, ah[m], al[m]);
      } else {
        ah[m] = pah[m];
        al[m] = pal[m];
      }
    }

    const int kn = (k0 + 32 < K) ? (k0 + 32) : 0;
    pbh = *(const bf16x8*)(Bhi + bstage + kn);
    pbl = *(const bf16x8*)(Blo + bstage + kn);
#pragma unroll
    for (int m = 0; m < 2; ++m) {
      if constexpr (AGATHER) {
        pga0[m] = *(const float4*)(Ag + abase[m] + kn);
        pga1[m] = *(const float4*)(Ag + abase[m] + kn + 4);
      } else {
        pah[m] = *(const bf16x8*)(Ahi + abase[m] + kn);
        pal[m] = *(const bf16x8*)(Alo + abase[m] + kn);
      }
    }
    __syncthreads();

    bf16x8 bhf[2], blf[2];
#pragma unroll
    for (int n = 0; n < 2; ++n) {
      bhf[n] = *(const bf16x8*)&bhS[cw + 16 * n + l15][8 * q];
      blf[n] = *(const bf16x8*)&blS[cw + 16 * n + l15][8 * q];
    }
#pragma unroll
    for (int m = 0; m < 2; ++m)
#pragma unroll
      for (int n = 0; n < 2; ++n) {
        acc[m][n] = __builtin_amdgcn_mfma_f32_16x16x32_bf16(ah[m], bhf[n], acc[m][n], 0, 0, 0);
        acc[m][n] = __builtin_amdgcn_mfma_f32_16x16x32_bf16(ah[m], blf[n], acc[m][n], 0, 0, 0);
        acc[m][n] = __builtin_amdgcn_mfma_f32_16x16x32_bf16(al[m], bhf[n], acc[m][n], 0, 0, 0);
      }
  }
}

__device__ __forceinline__ void store_tile256(f32x4 acc[2][2], float* __restrict__ C,
                                              int ldc, int n0)
{
  const int tid = threadIdx.x, lane = tid & 63, w = tid >> 6;
  const int l15 = lane & 15, q = lane >> 4;
  const int rw = (w >> 1) * 32, cw = (w & 1) * 32;
#pragma unroll
  for (int m = 0; m < 2; ++m)
#pragma unroll
    for (int n = 0; n < 2; ++n)
#pragma unroll
      for (int r = 0; r < 4; ++r)
        C[(size_t)(rw + 16 * m + 4 * q + r) * ldc + n0 + cw + 16 * n + l15] = acc[m][n][r];
}

// logits store(+bias, nontemporal) + fused gumbel-argmax partial (proven math)
__device__ __forceinline__ void sample_epi256(
    f32x4 acc[2][2], u64 (*__restrict__ scr)[2],
    const float* __restrict__ bias, float* __restrict__ C, int n0,
    u64* __restrict__ partial, int job, int t)
{
  const int tid = threadIdx.x, lane = tid & 63, w = tid >> 6;
  const int l15 = lane & 15, q = lane >> 4;
  const int rw = (w >> 1) * 32, cw = (w & 1) * 32;

  uint32_t kt0 = 0u, kt1 = (uint32_t)t;
  threefry2x32(0u, 42u, kt0, kt1);

  u64 bk[2][4];
#pragma unroll
  for (int m = 0; m < 2; ++m)
#pragma unroll
    for (int r = 0; r < 4; ++r) bk[m][r] = 0ull;

#pragma unroll
  for (int m = 0; m < 2; ++m)
#pragma unroll
    for (int n = 0; n < 2; ++n)
#pragma unroll
      for (int r = 0; r < 4; ++r) {
        int row = rw + 16 * m + 4 * q + r;          // batch index
        int col = n0 + cw + 16 * n + l15;           // vocab index
        float val = acc[m][n][r] + bias[col];
        __builtin_nontemporal_store(val, &C[(size_t)row * VV + col]);
        uint32_t c0 = 0u, c1 = (uint32_t)(row * VV + col);
        threefry2x32(kt0, kt1, c0, c1);
        uint32_t bits = c0 ^ c1;
        float u = __uint_as_float((bits >> 9) | 0x3f800000u) - 1.0f;
        if (u == 0.0f) u = 1.17549435e-38f;
        float g = -__logf(-__logf(u));
        bk[m][r] = umax64(bk[m][r], packkey(val + g, col));
      }
#pragma unroll
  for (int off = 1; off < 16; off <<= 1)
#pragma unroll
    for (int m = 0; m < 2; ++m)
#pragma unroll
      for (int r = 0; r < 4; ++r)
        bk[m][r] = umax64(bk[m][r], (u64)__shfl_xor((long long)bk[m][r], off, 64));

  if (l15 == 0) {
#pragma unroll
    for (int m = 0; m < 2; ++m)
#pragma unroll
      for (int r = 0; r < 4; ++r)
        scr[rw + 16 * m + 4 * q + r][w & 1] = bk[m][r];
  }
  __syncthreads();
  if (tid < 64)
    partial[(size_t)job * 64 + tid] = umax64(scr[tid][0], scr[tid][1]);
}

// block-local: reduce partial[500][64] -> idxS[64]
__device__ __forceinline__ void reduce_idx(
    int k, int eosv, const u64* __restrict__ partial,
    u64 (*__restrict__ fin)[4], int* __restrict__ idxS,
    float* __restrict__ idx_out, bool writeOut)
{
  const int tid = threadIdx.x;
  if (k < 0) {
    if (tid < 64) idxS[tid] = eosv;
    __syncthreads();
    return;
  }
  const int row = tid & 63, sub = tid >> 6;
  u64 best = 0;
  for (int i = sub; i < NT; i += 4)
    best = umax64(best, partial[(size_t)i * 64 + row]);
  fin[row][sub] = best;
  __syncthreads();
  if (tid < 64) {
    u64 b = umax64(umax64(fin[tid][0], fin[tid][1]),
                   umax64(fin[tid][2], fin[tid][3]));
    int idx = (int)(~(uint32_t)b);
    idxS[tid] = idx;
    if (writeOut) idx_out[(size_t)k * BB + tid] = (float)idx;
  }
  __syncthreads();
}

__device__ __forceinline__ void gh_job(
    int g, const ushort_t* __restrict__ hhi, const ushort_t* __restrict__ hlo,
    const ushort_t* __restrict__ whhH, const ushort_t* __restrict__ whhL,
    float* __restrict__ gh,
    ushort_t (*__restrict__ bhS)[LP], ushort_t (*__restrict__ blS)[LP])
{
  f32x4 acc[2][2] = {};
  tile256<false>(bhS, blS, hhi, hlo, nullptr, nullptr, HH, whhH, whhL, HH, g * 64, acc);
  store_tile256(acc, gh, G3, g * 64);
}

__device__ __forceinline__ void gi_job(
    int g, const float* __restrict__ emb, const int* __restrict__ idxS,
    const ushort_t* __restrict__ wihH, const ushort_t* __restrict__ wihL,
    float* __restrict__ gi,
    ushort_t (*__restrict__ bhS)[LP], ushort_t (*__restrict__ blS)[LP])
{
  f32x4 acc[2][2] = {};
  tile256<true>(bhS, blS, nullptr, nullptr, emb, idxS, DD, wihH, wihL, DD, g * 64, acc);
  store_tile256(acc, gi, G3, g * 64);
}

__device__ __forceinline__ void gru_math(
    const float* __restrict__ gir, const float* __restrict__ ghr,
    const float* __restrict__ bih, const float* __restrict__ bhh,
    float* __restrict__ h, ushort_t* __restrict__ hhi, ushort_t* __restrict__ hlo,
    int b, int j)
{
  float ir  = gir[j]        + bih[j],        hr = ghr[j]        + bhh[j];
  float iz  = gir[j + 1024] + bih[j + 1024], hz = ghr[j + 1024] + bhh[j + 1024];
  float in_ = gir[j + 2048] + bih[j + 2048], hn = ghr[j + 2048] + bhh[j + 2048];
  float r = 1.f / (1.f + expf(-(ir + hr)));
  float z = 1.f / (1.f + expf(-(iz + hz)));
  float n = tanhf(in_ + r * hn);
  int i = b * HH + j;
  float hv = (1.f - z) * n + z * h[i];
  h[i] = hv;
  uint32_t hb = f2bf(hv);
  hhi[i] = (ushort_t)hb;
  hlo[i] = (ushort_t)f2bf(hv - bf2f(hb));
}

__device__ __forceinline__ void fuse_all(
    int bid, int GRD,
    const float* __restrict__ gi, const float* __restrict__ gh,
    const float* __restrict__ bih, const float* __restrict__ bhh,
    float* __restrict__ h, ushort_t* __restrict__ hhi, ushort_t* __restrict__ hlo)
{
  for (int i = bid * 256 + threadIdx.x; i < BB * HH; i += GRD * 256) {
    int b = i >> 10, j = i & 1023;
    gru_math(gi + (size_t)b * G3, gh + (size_t)b * G3, bih, bhh, h, hhi, hlo, b, j);
  }
}

__device__ __forceinline__ void fuse_slice(
    int mb, const float* __restrict__ gi, const float* __restrict__ gh,
    const float* __restrict__ bih, const float* __restrict__ bhh,
    float* __restrict__ h, ushort_t* __restrict__ hhi, ushort_t* __restrict__ hlo)
{
  for (int e = threadIdx.x; e < 64 * 64; e += 256) {
    int b = e >> 6, j = mb * 64 + (e & 63);
    gru_math(gi + (size_t)b * G3, gh + (size_t)b * G3, bih, bhh, h, hhi, hlo, b, j);
  }
}

// S2 mega-block: reduce -> idx; 3 gi tiles {mb, mb+16, mb+32}; local fuse.
__device__ __forceinline__ void s2_body(
    int mb, int k, int eosv, const float* __restrict__ emb,
    const float* __restrict__ bih, const float* __restrict__ bhh,
    float* __restrict__ idx_out, const u64* __restrict__ partial,
    const ushort_t* __restrict__ wihH, const ushort_t* __restrict__ wihL,
    float* __restrict__ gi, const float* __restrict__ gh,
    float* __restrict__ h, ushort_t* __restrict__ hhi, ushort_t* __restrict__ hlo,
    ushort_t (*__restrict__ bhS)[LP], ushort_t (*__restrict__ blS)[LP],
    u64 (*__restrict__ fin)[4], int* __restrict__ idxS)
{
  reduce_idx(k, eosv, partial, fin, idxS, idx_out, mb == 0);
  if (k >= T_STEPS - 1) return;
#pragma unroll
  for (int g3 = 0; g3 < 3; ++g3)
    gi_job(mb + 16 * g3, emb, idxS, wihH, wihL, gi, bhS, blS);
  __threadfence_block();
  __syncthreads();
  fuse_slice(mb, gi, gh, bih, bhh, h, hhi, hlo);
}

__device__ __forceinline__ void prologue_body(
    const float* __restrict__ seq, const float* __restrict__ Wih,
    const float* __restrict__ Whh, const float* __restrict__ fcw,
    float* __restrict__ h0, ushort_t* __restrict__ h0hi, ushort_t* __restrict__ h0lo,
    ushort_t* __restrict__ wihH, ushort_t* __restrict__ wihL,
    ushort_t* __restrict__ whhH, ushort_t* __restrict__ whhL,
    ushort_t* __restrict__ fcwH, ushort_t* __restrict__ fcwL)
{
  long st = 4L * ((long)blockIdx.x * blockDim.x + threadIdx.x);
  long stride = 4L * (long)gridDim.x * blockDim.x;
  split_arr(Wih, wihH, wihL, (long)G3 * DD, st, stride);
  split_arr(Whh, whhH, whhL, (long)G3 * HH, st, stride);
  split_arr(fcw, fcwH, fcwL, (long)VV * HH, st, stride);
  for (long i = st; i < BB * HH; i += stride) {
    float4 v = *(const float4*)(seq + i);
    *(float4*)(h0 + i) = v;
    split_store4(v, h0hi, h0lo, i);
  }
}

// ---------------- kernels (multi-launch; L2 stays warm across launches) ----------------
__global__ __launch_bounds__(256) void k_pro(
    const float* seq, const float* Wih, const float* Whh, const float* fcw,
    float* h, ushort_t* hhi, ushort_t* hlo,
    ushort_t* wihH, ushort_t* wihL, ushort_t* whhH, ushort_t* whhL,
    ushort_t* fcwH, ushort_t* fcwL)
{
  prologue_body(seq, Wih, Whh, fcw, h, hhi, hlo,
                wihH, wihL, whhH, whhL, fcwH, fcwL);
}

__global__ __launch_bounds__(256, 4) void k_pre(
    const int* eos, const float* emb,
    const ushort_t* hhi, const ushort_t* hlo,
    const ushort_t* wihH, const ushort_t* wihL,
    const ushort_t* whhH, const ushort_t* whhL,
    float* gi, float* gh)
{
  __shared__ ushort_t bhS[64][LP];
  __shared__ ushort_t blS[64][LP];
  __shared__ int idxS[64];
  if (threadIdx.x < 64) idxS[threadIdx.x] = eos[0];
  __syncthreads();
  int job = blockIdx.x;
  if (job < NGH) gh_job(job, hhi, hlo, whhH, whhL, gh, bhS, blS);
  else           gi_job(job - NGH, emb, idxS, wihH, wihL, gi, bhS, blS);
}

__global__ __launch_bounds__(256) void k_fuse(
    const float* gi, const float* gh, const float* bih, const float* bhh,
    float* h, ushort_t* hhi, ushort_t* hlo)
{
  fuse_all(blockIdx.x, gridDim.x, gi, gh, bih, bhh, h, hhi, hlo);
}

__global__ __launch_bounds__(256, 4) void k_s1(
    int k, const ushort_t* __restrict__ hhi, const ushort_t* __restrict__ hlo,
    const ushort_t* __restrict__ fcwH, const ushort_t* __restrict__ fcwL,
    const float* __restrict__ fcb,
    const ushort_t* __restrict__ whhH, const ushort_t* __restrict__ whhL,
    float* __restrict__ log_out, float* __restrict__ gh, u64* __restrict__ partial)
{
  __shared__ ushort_t bhS[64][LP];
  __shared__ ushort_t blS[64][LP];
  __shared__ u64 scr[64][2];
  int job = blockIdx.x;
  if (job < NT) {
    f32x4 acc[2][2] = {};
    tile256<false>(bhS, blS, hhi, hlo, nullptr, nullptr, HH,
                   fcwH, fcwL, HH, job * 64, acc);
    sample_epi256(acc, scr, fcb, log_out + (size_t)k * BB * VV, job * 64,
                  partial, job, k);
  } else {
    gh_job(job - NT, hhi, hlo, whhH, whhL, gh, bhS, blS);
  }
}

__global__ __launch_bounds__(256, 4) void k_s2(
    int k, const int* __restrict__ eos, const float* __restrict__ emb,
    const float* __restrict__ bih, const float* __restrict__ bhh,
    float* __restrict__ idx_out, const u64* __restrict__ partial,
    const ushort_t* __restrict__ wihH, const ushort_t* __restrict__ wihL,
    float* __restrict__ gi, const float* __restrict__ gh,
    float* __restrict__ h, ushort_t* __restrict__ hhi, ushort_t* __restrict__ hlo)
{
  __shared__ ushort_t bhS[64][LP];
  __shared__ ushort_t blS[64][LP];
  __shared__ u64 fin[64][4];
  __shared__ int idxS[64];
  s2_body(blockIdx.x, k, eos[0], emb, bih, bhh, idx_out, partial,
          wihH, wihL, gi, gh, h, hhi, hlo, bhS, blS, fin, idxS);
}

extern "C" void kernel_launch(void* const* d_in, const int* in_sizes, int n_in,
                              void* d_out, int out_size, void* d_ws, size_t ws_size,
                              hipStream_t stream) {
  const float* seq = (const float*)d_in[0];
  const float* emb = (const float*)d_in[1];
  const float* Wih = (const float*)d_in[2];
  const float* Whh = (const float*)d_in[3];
  const float* bih = (const float*)d_in[4];
  const float* bhh = (const float*)d_in[5];
  const float* fcw = (const float*)d_in[6];
  const float* fcb = (const float*)d_in[7];
  const int*   eos = (const int*)d_in[8];

  float* out = (float*)d_out;
  float* idx_out = out;                              // [50][64] as float
  float* log_out = out + (size_t)T_STEPS * BB;       // [50][64][32000]

  uint8_t* wsp = (uint8_t*)d_ws;
  auto alloc = [&](size_t bytes) {
    uint8_t* p = wsp;
    wsp += (bytes + 255) & ~(size_t)255;
    return p;
  };
  float*    h    = (float*)alloc((size_t)BB * HH * 4);
  ushort_t* hhi  = (ushort_t*)alloc((size_t)BB * HH * 2);
  ushort_t* hlo  = (ushort_t*)alloc((size_t)BB * HH * 2);
  float*    gi   = (float*)alloc((size_t)BB * G3 * 4);
  float*    gh   = (float*)alloc((size_t)BB * G3 * 4);
  u64*      part = (u64*)alloc((size_t)NT * 64 * 8);
  ushort_t* wihH = (ushort_t*)alloc((size_t)G3 * DD * 2);
  ushort_t* wihL = (ushort_t*)alloc((size_t)G3 * DD * 2);
  ushort_t* whhH = (ushort_t*)alloc((size_t)G3 * HH * 2);
  ushort_t* whhL = (ushort_t*)alloc((size_t)G3 * HH * 2);
  ushort_t* fcwH = (ushort_t*)alloc((size_t)VV * HH * 2);
  ushort_t* fcwL = (ushort_t*)alloc((size_t)VV * HH * 2);

  // no cooperative kernel: grid.sync invalidates per-XCD L2 every step
  // (rounds 4-8 evidence). Plain dependent launches keep L2 warm.
  k_pro<<<2048, 256, 0, stream>>>(seq, Wih, Whh, fcw, h, hhi, hlo,
                                  wihH, wihL, whhH, whhL, fcwH, fcwL);
  k_pre<<<2 * NGH, 256, 0, stream>>>(eos, emb, hhi, hlo, wihH, wihL,
                                     whhH, whhL, gi, gh);
  k_fuse<<<256, 256, 0, stream>>>(gi, gh, bih, bhh, h, hhi, hlo);
  for (int k = 0; k < T_STEPS; ++k) {
    int njob = (k < T_STEPS - 1) ? (NT + NGH) : NT;
    k_s1<<<njob, 256, 0, stream>>>(k, hhi, hlo, fcwH, fcwL, fcb,
                                   whhH, whhL, log_out, gh, part);
    k_s2<<<NS2, 256, 0, stream>>>(k, eos, emb, bih, bhh, idx_out, part,
                                  wihH, wihL, gi, gh, h, hhi, hlo);
  }
}

// Round 10
// 6694.840 us; speedup vs baseline: 2.2281x; 1.2228x over previous
//
#include <hip/hip_runtime.h>
#include <stdint.h>

#define BB 64
#define DD 512
#define HH 1024
#define VV 32000
#define T_STEPS 50
#define G3 3072
#define NT 500      // logits col-tiles (64 cols each)
#define NGH 48      // gate col-tiles (64 cols each)
#define NS2 16      // fuse slices (64 hidden cols each)
#define LP 42       // LDS row stride (ushorts): 21 dwords, gcd(21,32)=1

typedef __attribute__((ext_vector_type(8))) short bf16x8;
typedef __attribute__((ext_vector_type(4))) float f32x4;
typedef unsigned long long u64;
typedef unsigned short ushort_t;

__device__ __forceinline__ uint32_t rotl32(uint32_t x, int d) {
  return (x << d) | (x >> (32 - d));
}

// JAX threefry2x32 (20 rounds) — verified exact in rounds 1-9.
__device__ __forceinline__ void threefry2x32(uint32_t k0, uint32_t k1,
                                             uint32_t& x0, uint32_t& x1) {
  uint32_t ks0 = k0, ks1 = k1, ks2 = k0 ^ k1 ^ 0x1BD11BDAu;
  x0 += ks0; x1 += ks1;
#define TF_R(r) { x0 += x1; x1 = rotl32(x1, (r)); x1 ^= x0; }
  TF_R(13) TF_R(15) TF_R(26) TF_R(6)
  x0 += ks1; x1 += ks2 + 1u;
  TF_R(17) TF_R(29) TF_R(16) TF_R(24)
  x0 += ks2; x1 += ks0 + 2u;
  TF_R(13) TF_R(15) TF_R(26) TF_R(6)
  x0 += ks0; x1 += ks1 + 3u;
  TF_R(17) TF_R(29) TF_R(16) TF_R(24)
  x0 += ks1; x1 += ks2 + 4u;
  TF_R(13) TF_R(15) TF_R(26) TF_R(6)
  x0 += ks2; x1 += ks0 + 5u;
#undef TF_R
}

__device__ __forceinline__ uint32_t f2bf(float f) {
  uint32_t u = __float_as_uint(f);
  return (u + 0x7fffu + ((u >> 16) & 1u)) >> 16;
}
__device__ __forceinline__ float bf2f(uint32_t b) { return __uint_as_float(b << 16); }

__device__ __forceinline__ u64 packkey(float v, int c) {
  uint32_t s = __float_as_uint(v);
  uint32_t mo = (s & 0x80000000u) ? ~s : (s | 0x80000000u);
  return ((u64)mo << 32) | (uint32_t)(~(uint32_t)c);
}
__device__ __forceinline__ u64 umax64(u64 a, u64 b) { return a > b ? a : b; }

union BF8 { uint32_t u[4]; bf16x8 v; };

__device__ __forceinline__ void split8(const float* f, bf16x8& hi, bf16x8& lo) {
  BF8 H, L;
#pragma unroll
  for (int i = 0; i < 4; ++i) {
    float a = f[2 * i], b = f[2 * i + 1];
    uint32_t ha = f2bf(a), hb = f2bf(b);
    float ra = a - bf2f(ha), rb = b - bf2f(hb);
    H.u[i] = ha | (hb << 16);
    L.u[i] = f2bf(ra) | (f2bf(rb) << 16);
  }
  hi = H.v; lo = L.v;
}

__device__ __forceinline__ void split_store4(const float4 v, ushort_t* hi,
                                             ushort_t* lo, long i) {
  uint32_t h0 = f2bf(v.x), h1 = f2bf(v.y), h2 = f2bf(v.z), h3 = f2bf(v.w);
  uint32_t l0 = f2bf(v.x - bf2f(h0)), l1 = f2bf(v.y - bf2f(h1));
  uint32_t l2 = f2bf(v.z - bf2f(h2)), l3 = f2bf(v.w - bf2f(h3));
  *(uint2*)(hi + i) = make_uint2(h0 | (h1 << 16), h2 | (h3 << 16));
  *(uint2*)(lo + i) = make_uint2(l0 | (l1 << 16), l2 | (l3 << 16));
}

__device__ void split_arr(const float* __restrict__ s, ushort_t* __restrict__ hi,
                          ushort_t* __restrict__ lo, long n, long st, long stride) {
  for (long i = st; i < n; i += stride) {
    float4 v = *(const float4*)(s + i);
    split_store4(v, hi, lo, i);
  }
}

// 256-thread 64x64 tile: register prefetch + DOUBLE-BUFFERED LDS (1 barrier/iter).
// B: pre-split bf16 hi/lo. A: pre-split bf16 rows or gathered fp32 rows.
template<bool AGATHER>
__device__ __forceinline__ void tile256(
    ushort_t (*__restrict__ bhS)[64][LP], ushort_t (*__restrict__ blS)[64][LP],
    const ushort_t* __restrict__ Ahi, const ushort_t* __restrict__ Alo,
    const float* __restrict__ Ag, const int* __restrict__ rowidx, int lda,
    const ushort_t* __restrict__ Bhi, const ushort_t* __restrict__ Blo,
    int K, int n0, f32x4 acc[2][2])
{
  const int tid = threadIdx.x, lane = tid & 63, w = tid >> 6;
  const int l15 = lane & 15, q = lane >> 4;
  const int rw = (w >> 1) * 32, cw = (w & 1) * 32;
  const int srow = tid >> 2, schunk = (tid & 3) * 8;

  size_t abase[2];
#pragma unroll
  for (int m = 0; m < 2; ++m) {
    int r = rw + 16 * m + l15;
    abase[m] = (size_t)(AGATHER ? rowidx[r] : r) * lda + 8 * q;
  }
  const size_t bstage = (size_t)(n0 + srow) * K + schunk;

  bf16x8 pbh = *(const bf16x8*)(Bhi + bstage);
  bf16x8 pbl = *(const bf16x8*)(Blo + bstage);
  bf16x8 pah[2], pal[2];
  float4 pga0[2], pga1[2];
#pragma unroll
  for (int m = 0; m < 2; ++m) {
    if constexpr (AGATHER) {
      pga0[m] = *(const float4*)(Ag + abase[m]);
      pga1[m] = *(const float4*)(Ag + abase[m] + 4);
    } else {
      pah[m] = *(const bf16x8*)(Ahi + abase[m]);
      pal[m] = *(const bf16x8*)(Alo + abase[m]);
    }
  }

  for (int k0 = 0; k0 < K; k0 += 32) {
    const int c = (k0 >> 5) & 1;
    *(bf16x8*)&bhS[c][srow][schunk] = pbh;
    *(bf16x8*)&blS[c][srow][schunk] = pbl;

    bf16x8 ah[2], al[2];
#pragma unroll
    for (int m = 0; m < 2; ++m) {
      if constexpr (AGATHER) {
        float f[8] = {pga0[m].x, pga0[m].y, pga0[m].z, pga0[m].w,
                      pga1[m].x, pga1[m].y, pga1[m].z, pga1[m].w};
        split8(f, ah[m], al[m]);
      } else {
        ah[m] = pah[m];
        al[m] = pal[m];
      }
    }

    const int kn = (k0 + 32 < K) ? (k0 + 32) : 0;
    pbh = *(const bf16x8*)(Bhi + bstage + kn);
    pbl = *(const bf16x8*)(Blo + bstage + kn);
#pragma unroll
    for (int m = 0; m < 2; ++m) {
      if constexpr (AGATHER) {
        pga0[m] = *(const float4*)(Ag + abase[m] + kn);
        pga1[m] = *(const float4*)(Ag + abase[m] + kn + 4);
      } else {
        pah[m] = *(const bf16x8*)(Ahi + abase[m] + kn);
        pal[m] = *(const bf16x8*)(Alo + abase[m] + kn);
      }
    }
    __syncthreads();   // buf c staged; prior iter's reads (other buf) done

    bf16x8 bhf[2], blf[2];
#pragma unroll
    for (int n = 0; n < 2; ++n) {
      bhf[n] = *(const bf16x8*)&bhS[c][cw + 16 * n + l15][8 * q];
      blf[n] = *(const bf16x8*)&blS[c][cw + 16 * n + l15][8 * q];
    }
#pragma unroll
    for (int m = 0; m < 2; ++m)
#pragma unroll
      for (int n = 0; n < 2; ++n) {
        acc[m][n] = __builtin_amdgcn_mfma_f32_16x16x32_bf16(ah[m], bhf[n], acc[m][n], 0, 0, 0);
        acc[m][n] = __builtin_amdgcn_mfma_f32_16x16x32_bf16(ah[m], blf[n], acc[m][n], 0, 0, 0);
        acc[m][n] = __builtin_amdgcn_mfma_f32_16x16x32_bf16(al[m], bhf[n], acc[m][n], 0, 0, 0);
      }
  }
}

__device__ __forceinline__ void store_tile256(f32x4 acc[2][2], float* __restrict__ C,
                                              int ldc, int n0)
{
  const int tid = threadIdx.x, lane = tid & 63, w = tid >> 6;
  const int l15 = lane & 15, q = lane >> 4;
  const int rw = (w >> 1) * 32, cw = (w & 1) * 32;
#pragma unroll
  for (int m = 0; m < 2; ++m)
#pragma unroll
    for (int n = 0; n < 2; ++n)
#pragma unroll
      for (int r = 0; r < 4; ++r)
        C[(size_t)(rw + 16 * m + 4 * q + r) * ldc + n0 + cw + 16 * n + l15] = acc[m][n][r];
}

// logits store(+bias, nontemporal) + fused gumbel-argmax partial (proven math)
__device__ __forceinline__ void sample_epi256(
    f32x4 acc[2][2], u64 (*__restrict__ scr)[2],
    const float* __restrict__ bias, float* __restrict__ C, int n0,
    u64* __restrict__ partial, int job, int t)
{
  const int tid = threadIdx.x, lane = tid & 63, w = tid >> 6;
  const int l15 = lane & 15, q = lane >> 4;
  const int rw = (w >> 1) * 32, cw = (w & 1) * 32;

  uint32_t kt0 = 0u, kt1 = (uint32_t)t;
  threefry2x32(0u, 42u, kt0, kt1);

  u64 bk[2][4];
#pragma unroll
  for (int m = 0; m < 2; ++m)
#pragma unroll
    for (int r = 0; r < 4; ++r) bk[m][r] = 0ull;

#pragma unroll
  for (int m = 0; m < 2; ++m)
#pragma unroll
    for (int n = 0; n < 2; ++n)
#pragma unroll
      for (int r = 0; r < 4; ++r) {
        int row = rw + 16 * m + 4 * q + r;          // batch index
        int col = n0 + cw + 16 * n + l15;           // vocab index
        float val = acc[m][n][r] + bias[col];
        __builtin_nontemporal_store(val, &C[(size_t)row * VV + col]);
        uint32_t c0 = 0u, c1 = (uint32_t)(row * VV + col);
        threefry2x32(kt0, kt1, c0, c1);
        uint32_t bits = c0 ^ c1;
        float u = __uint_as_float((bits >> 9) | 0x3f800000u) - 1.0f;
        if (u == 0.0f) u = 1.17549435e-38f;
        float g = -__logf(-__logf(u));
        bk[m][r] = umax64(bk[m][r], packkey(val + g, col));
      }
#pragma unroll
  for (int off = 1; off < 16; off <<= 1)
#pragma unroll
    for (int m = 0; m < 2; ++m)
#pragma unroll
      for (int r = 0; r < 4; ++r)
        bk[m][r] = umax64(bk[m][r], (u64)__shfl_xor((long long)bk[m][r], off, 64));

  if (l15 == 0) {
#pragma unroll
    for (int m = 0; m < 2; ++m)
#pragma unroll
      for (int r = 0; r < 4; ++r)
        scr[rw + 16 * m + 4 * q + r][w & 1] = bk[m][r];
  }
  __syncthreads();
  if (tid < 64)
    partial[(size_t)job * 64 + tid] = umax64(scr[tid][0], scr[tid][1]);
}

// block-local: reduce partial[500][64] -> idxS[64]
__device__ __forceinline__ void reduce_idx(
    int k, const u64* __restrict__ partial,
    u64 (*__restrict__ fin)[4], int* __restrict__ idxS,
    float* __restrict__ idx_out, bool writeOut)
{
  const int tid = threadIdx.x;
  const int row = tid & 63, sub = tid >> 6;
  u64 best = 0;
  for (int i = sub; i < NT; i += 4)
    best = umax64(best, partial[(size_t)i * 64 + row]);
  fin[row][sub] = best;
  __syncthreads();
  if (tid < 64) {
    u64 b = umax64(umax64(fin[tid][0], fin[tid][1]),
                   umax64(fin[tid][2], fin[tid][3]));
    int idx = (int)(~(uint32_t)b);
    idxS[tid] = idx;
    if (writeOut) idx_out[(size_t)k * BB + tid] = (float)idx;
  }
  __syncthreads();
}

__device__ __forceinline__ void gh_job(
    int g, const ushort_t* __restrict__ hhi, const ushort_t* __restrict__ hlo,
    const ushort_t* __restrict__ whhH, const ushort_t* __restrict__ whhL,
    float* __restrict__ gh,
    ushort_t (*__restrict__ bhS)[64][LP], ushort_t (*__restrict__ blS)[64][LP])
{
  f32x4 acc[2][2] = {};
  tile256<false>(bhS, blS, hhi, hlo, nullptr, nullptr, HH, whhH, whhL, HH, g * 64, acc);
  store_tile256(acc, gh, G3, g * 64);
}

__device__ __forceinline__ void gi_job(
    int g, const float* __restrict__ emb, const int* __restrict__ idxS,
    const ushort_t* __restrict__ wihH, const ushort_t* __restrict__ wihL,
    float* __restrict__ gi,
    ushort_t (*__restrict__ bhS)[64][LP], ushort_t (*__restrict__ blS)[64][LP])
{
  f32x4 acc[2][2] = {};
  tile256<true>(bhS, blS, nullptr, nullptr, emb, idxS, DD, wihH, wihL, DD, g * 64, acc);
  store_tile256(acc, gi, G3, g * 64);
}

__device__ __forceinline__ void gru_math(
    const float* __restrict__ gir, const float* __restrict__ ghr,
    const float* __restrict__ bih, const float* __restrict__ bhh,
    float* __restrict__ h, ushort_t* __restrict__ hhi, ushort_t* __restrict__ hlo,
    int b, int j)
{
  float ir  = gir[j]        + bih[j],        hr = ghr[j]        + bhh[j];
  float iz  = gir[j + 1024] + bih[j + 1024], hz = ghr[j + 1024] + bhh[j + 1024];
  float in_ = gir[j + 2048] + bih[j + 2048], hn = ghr[j + 2048] + bhh[j + 2048];
  float r = 1.f / (1.f + expf(-(ir + hr)));
  float z = 1.f / (1.f + expf(-(iz + hz)));
  float n = tanhf(in_ + r * hn);
  int i = b * HH + j;
  float hv = (1.f - z) * n + z * h[i];
  h[i] = hv;
  uint32_t hb = f2bf(hv);
  hhi[i] = (ushort_t)hb;
  hlo[i] = (ushort_t)f2bf(hv - bf2f(hb));
}

__device__ __forceinline__ void fuse_all(
    int bid, int GRD,
    const float* __restrict__ gi, const float* __restrict__ gh,
    const float* __restrict__ bih, const float* __restrict__ bhh,
    float* __restrict__ h, ushort_t* __restrict__ hhi, ushort_t* __restrict__ hlo)
{
  for (int i = bid * 256 + threadIdx.x; i < BB * HH; i += GRD * 256) {
    int b = i >> 10, j = i & 1023;
    gru_math(gi + (size_t)b * G3, gh + (size_t)b * G3, bih, bhh, h, hhi, hlo, b, j);
  }
}

__device__ __forceinline__ void fuse_slice(
    int mb, const float* __restrict__ gi, const float* __restrict__ gh,
    const float* __restrict__ bih, const float* __restrict__ bhh,
    float* __restrict__ h, ushort_t* __restrict__ hhi, ushort_t* __restrict__ hlo)
{
  for (int e = threadIdx.x; e < 64 * 64; e += 256) {
    int b = e >> 6, j = mb * 64 + (e & 63);
    gru_math(gi + (size_t)b * G3, gh + (size_t)b * G3, bih, bhh, h, hhi, hlo, b, j);
  }
}

__device__ __forceinline__ void prologue_body(
    const float* __restrict__ seq, const float* __restrict__ Wih,
    const float* __restrict__ Whh, const float* __restrict__ fcw,
    float* __restrict__ h0, ushort_t* __restrict__ h0hi, ushort_t* __restrict__ h0lo,
    ushort_t* __restrict__ wihH, ushort_t* __restrict__ wihL,
    ushort_t* __restrict__ whhH, ushort_t* __restrict__ whhL,
    ushort_t* __restrict__ fcwH, ushort_t* __restrict__ fcwL)
{
  long st = 4L * ((long)blockIdx.x * blockDim.x + threadIdx.x);
  long stride = 4L * (long)gridDim.x * blockDim.x;
  split_arr(Wih, wihH, wihL, (long)G3 * DD, st, stride);
  split_arr(Whh, whhH, whhL, (long)G3 * HH, st, stride);
  split_arr(fcw, fcwH, fcwL, (long)VV * HH, st, stride);
  for (long i = st; i < BB * HH; i += stride) {
    float4 v = *(const float4*)(seq + i);
    *(float4*)(h0 + i) = v;
    split_store4(v, h0hi, h0lo, i);
  }
}

// ---------------- kernels ----------------
__global__ __launch_bounds__(256) void k_pro(
    const float* seq, const float* Wih, const float* Whh, const float* fcw,
    float* h, ushort_t* hhi, ushort_t* hlo,
    ushort_t* wihH, ushort_t* wihL, ushort_t* whhH, ushort_t* whhL,
    ushort_t* fcwH, ushort_t* fcwL, int* ctrA, int* sctrA)
{
  int gidx = blockIdx.x * 256 + threadIdx.x;
  if (gidx < T_STEPS) ctrA[gidx] = 0;
  if (gidx < T_STEPS * NS2) sctrA[gidx] = 0;
  prologue_body(seq, Wih, Whh, fcw, h, hhi, hlo,
                wihH, wihL, whhH, whhL, fcwH, fcwL);
}

__global__ __launch_bounds__(256, 4) void k_pre(
    const int* eos, const float* emb,
    const ushort_t* hhi, const ushort_t* hlo,
    const ushort_t* wihH, const ushort_t* wihL,
    const ushort_t* whhH, const ushort_t* whhL,
    float* gi, float* gh)
{
  __shared__ ushort_t bhS[2][64][LP];
  __shared__ ushort_t blS[2][64][LP];
  __shared__ int idxS[64];
  if (threadIdx.x < 64) idxS[threadIdx.x] = eos[0];
  __syncthreads();
  int job = blockIdx.x;
  if (job < NGH) gh_job(job, hhi, hlo, whhH, whhL, gh, bhS, blS);
  else           gi_job(job - NGH, emb, idxS, wihH, wihL, gi, bhS, blS);
}

__global__ __launch_bounds__(256) void k_fuse(
    const float* gi, const float* gh, const float* bih, const float* bhh,
    float* h, ushort_t* hhi, ushort_t* hlo)
{
  fuse_all(blockIdx.x, gridDim.x, gi, gh, bih, bhh, h, hhi, hlo);
}

// ---- the whole decode step in ONE launch (producer-consumer, no grid.sync) ----
__global__ __launch_bounds__(256, 4) void k_step(
    int k, int last,
    const float* __restrict__ emb, const float* __restrict__ bih,
    const float* __restrict__ bhh, const float* __restrict__ fcb,
    float* __restrict__ idx_out, float* __restrict__ log_out,
    float* __restrict__ h, ushort_t* __restrict__ hhi, ushort_t* __restrict__ hlo,
    float* __restrict__ gi, float* __restrict__ gh, u64* __restrict__ partial,
    const ushort_t* __restrict__ wihH, const ushort_t* __restrict__ wihL,
    const ushort_t* __restrict__ whhH, const ushort_t* __restrict__ whhL,
    const ushort_t* __restrict__ fcwH, const ushort_t* __restrict__ fcwL,
    int* __restrict__ ctr, int* __restrict__ sctr)
{
  __shared__ ushort_t bhS[2][64][LP];
  __shared__ ushort_t blS[2][64][LP];
  __shared__ u64 scr[64][2];
  __shared__ u64 fin[64][4];
  __shared__ int idxS[64];
  __shared__ int sOld;
  const int bid = blockIdx.x, tid = threadIdx.x;

  if (bid < NT) {
    // logits tile + sampling partials (reads h_{k+1} via hhi/hlo)
    f32x4 acc[2][2] = {};
    tile256<false>(bhS, blS, hhi, hlo, nullptr, nullptr, HH,
                   fcwH, fcwL, HH, bid * 64, acc);
    sample_epi256(acc, scr, fcb, log_out + (size_t)k * BB * VV, bid * 64,
                  partial, bid, k);
    __threadfence();
    __syncthreads();
    if (tid == 0) atomicAdd(ctr, 1);
  } else if (bid < NT + NGH) {
    // gh = Whh @ h_{k+1} for the next cell
    if (!last) {
      gh_job(bid - NT, hhi, hlo, whhH, whhL, gh, bhS, blS);
      __threadfence();
    }
    __syncthreads();
    if (tid == 0) atomicAdd(ctr, 1);
  } else {
    // consumer: wait for all partials+gh, then reduce -> idx -> gi -> fuse
    const int g = bid - (NT + NGH);
    if (tid == 0) {
      while (atomicAdd(ctr, 0) < NT + NGH) __builtin_amdgcn_s_sleep(8);
    }
    __syncthreads();
    __threadfence();
    reduce_idx(k, partial, fin, idxS, idx_out, g == 0);
    if (!last) {
      gi_job(g, emb, idxS, wihH, wihL, gi, bhS, blS);
      __threadfence();
      __syncthreads();
      if (tid == 0) sOld = atomicAdd(&sctr[g & (NS2 - 1)], 1);
      __syncthreads();
      if (sOld == 2) {          // last of the 3 gate-tiles for this slice
        __threadfence();
        fuse_slice(g & (NS2 - 1), gi, gh, bih, bhh, h, hhi, hlo);
      }
    }
  }
}

// ---- round-9 style two-kernel step (fallback if co-residency not guaranteed) ----
__global__ __launch_bounds__(256, 4) void k_s1(
    int k, const ushort_t* __restrict__ hhi, const ushort_t* __restrict__ hlo,
    const ushort_t* __restrict__ fcwH, const ushort_t* __restrict__ fcwL,
    const float* __restrict__ fcb,
    const ushort_t* __restrict__ whhH, const ushort_t* __restrict__ whhL,
    float* __restrict__ log_out, float* __restrict__ gh, u64* __restrict__ partial)
{
  __shared__ ushort_t bhS[2][64][LP];
  __shared__ ushort_t blS[2][64][LP];
  __shared__ u64 scr[64][2];
  int job = blockIdx.x;
  if (job < NT) {
    f32x4 acc[2][2] = {};
    tile256<false>(bhS, blS, hhi, hlo, nullptr, nullptr, HH,
                   fcwH, fcwL, HH, job * 64, acc);
    sample_epi256(acc, scr, fcb, log_out + (size_t)k * BB * VV, job * 64,
                  partial, job, k);
  } else {
    gh_job(job - NT, hhi, hlo, whhH, whhL, gh, bhS, blS);
  }
}

__global__ __launch_bounds__(256, 4) void k_s2(
    int k, int last, const float* __restrict__ emb,
    const float* __restrict__ bih, const float* __restrict__ bhh,
    float* __restrict__ idx_out, const u64* __restrict__ partial,
    const ushort_t* __restrict__ wihH, const ushort_t* __restrict__ wihL,
    float* __restrict__ gi, const float* __restrict__ gh,
    float* __restrict__ h, ushort_t* __restrict__ hhi, ushort_t* __restrict__ hlo,
    int* __restrict__ sctr)
{
  __shared__ ushort_t bhS[2][64][LP];
  __shared__ ushort_t blS[2][64][LP];
  __shared__ u64 fin[64][4];
  __shared__ int idxS[64];
  __shared__ int sOld;
  const int g = blockIdx.x, tid = threadIdx.x;
  reduce_idx(k, partial, fin, idxS, idx_out, g == 0);
  if (!last) {
    gi_job(g, emb, idxS, wihH, wihL, gi, bhS, blS);
    __threadfence();
    __syncthreads();
    if (tid == 0) sOld = atomicAdd(&sctr[g & (NS2 - 1)], 1);
    __syncthreads();
    if (sOld == 2) {
      __threadfence();
      fuse_slice(g & (NS2 - 1), gi, gh, bih, bhh, h, hhi, hlo);
    }
  }
}

extern "C" void kernel_launch(void* const* d_in, const int* in_sizes, int n_in,
                              void* d_out, int out_size, void* d_ws, size_t ws_size,
                              hipStream_t stream) {
  const float* seq = (const float*)d_in[0];
  const float* emb = (const float*)d_in[1];
  const float* Wih = (const float*)d_in[2];
  const float* Whh = (const float*)d_in[3];
  const float* bih = (const float*)d_in[4];
  const float* bhh = (const float*)d_in[5];
  const float* fcw = (const float*)d_in[6];
  const float* fcb = (const float*)d_in[7];
  const int*   eos = (const int*)d_in[8];

  float* out = (float*)d_out;
  float* idx_out = out;                              // [50][64] as float
  float* log_out = out + (size_t)T_STEPS * BB;       // [50][64][32000]

  uint8_t* wsp = (uint8_t*)d_ws;
  auto alloc = [&](size_t bytes) {
    uint8_t* p = wsp;
    wsp += (bytes + 255) & ~(size_t)255;
    return p;
  };
  float*    h     = (float*)alloc((size_t)BB * HH * 4);
  ushort_t* hhi   = (ushort_t*)alloc((size_t)BB * HH * 2);
  ushort_t* hlo   = (ushort_t*)alloc((size_t)BB * HH * 2);
  float*    gi    = (float*)alloc((size_t)BB * G3 * 4);
  float*    gh    = (float*)alloc((size_t)BB * G3 * 4);
  u64*      part  = (u64*)alloc((size_t)NT * 64 * 8);
  int*      ctrA  = (int*)alloc((size_t)T_STEPS * 4);
  int*      sctrA = (int*)alloc((size_t)T_STEPS * NS2 * 4);
  ushort_t* wihH  = (ushort_t*)alloc((size_t)G3 * DD * 2);
  ushort_t* wihL  = (ushort_t*)alloc((size_t)G3 * DD * 2);
  ushort_t* whhH  = (ushort_t*)alloc((size_t)G3 * HH * 2);
  ushort_t* whhL  = (ushort_t*)alloc((size_t)G3 * HH * 2);
  ushort_t* fcwH  = (ushort_t*)alloc((size_t)VV * HH * 2);
  ushort_t* fcwL  = (ushort_t*)alloc((size_t)VV * HH * 2);

  k_pro<<<2048, 256, 0, stream>>>(seq, Wih, Whh, fcw, h, hhi, hlo,
                                  wihH, wihL, whhH, whhL, fcwH, fcwL,
                                  ctrA, sctrA);
  k_pre<<<2 * NGH, 256, 0, stream>>>(eos, emb, hhi, hlo, wihH, wihL,
                                     whhH, whhL, gi, gh);
  k_fuse<<<256, 256, 0, stream>>>(gi, gh, bih, bhh, h, hhi, hlo);   // -> h_1

  // co-residency check for the producer-consumer kernel (deadlock guard)
  int dev = 0;
  (void)hipGetDevice(&dev);
  int numCU = 0;
  (void)hipDeviceGetAttribute(&numCU, hipDeviceAttributeMultiprocessorCount, dev);
  int occ = 0;
  hipError_t qe = hipOccupancyMaxActiveBlocksPerMultiprocessor(
      &occ, reinterpret_cast<const void*>(&k_step), 256, 0);
  const int GRID = NT + NGH + NGH;   // 596
  bool safe = (qe == hipSuccess) && ((long)occ * numCU >= GRID);

  if (safe) {
    for (int k = 0; k < T_STEPS; ++k)
      k_step<<<GRID, 256, 0, stream>>>(k, (k == T_STEPS - 1) ? 1 : 0,
                                       emb, bih, bhh, fcb, idx_out, log_out,
                                       h, hhi, hlo, gi, gh, part,
                                       wihH, wihL, whhH, whhL, fcwH, fcwL,
                                       ctrA + k, sctrA + (size_t)k * NS2);
  } else {
    for (int k = 0; k < T_STEPS; ++k) {
      int last = (k == T_STEPS - 1) ? 1 : 0;
      int njob = last ? NT : (NT + NGH);
      k_s1<<<njob, 256, 0, stream>>>(k, hhi, hlo, fcwH, fcwL, fcb,
                                     whhH, whhL, log_out, gh, part);
      k_s2<<<NGH, 256, 0, stream>>>(k, last, emb, bih, bhh, idx_out, part,
                                    wihH, wihL, gi, gh, h, hhi, hlo,
                                    sctrA + (size_t)k * NS2);
    }
  }
}